// Round 13
// baseline (221.234 us; speedup 1.0000x reference)
//
#include <hip/hip_runtime.h>
#include <math.h>

#define B_    2
#define T_    2048
#define C_    512
#define NB_   4
#define HALF_ 256
#define BT_   (B_*T_)
#define EPS_  1.1920929e-07f
#define RSC_  0.044194173824159216f   // 1/sqrt(512)

using f32x4 = __attribute__((ext_vector_type(4))) float;
using s16x8 = __attribute__((ext_vector_type(8))) short;
using u16x8 = __attribute__((ext_vector_type(8))) unsigned short;

__device__ __forceinline__ unsigned short f2bf(float f) {
    unsigned x = __float_as_uint(f);
    unsigned r = (x + 0x7fffu + ((x >> 16) & 1u)) >> 16;
    return (unsigned short)r;
}
__device__ __forceinline__ float bf2f(unsigned short h) {
    return __uint_as_float(((unsigned)h) << 16);
}

// direct global->LDS 16B: per-lane global src, wave-uniform LDS base (+lane*16B in HW)
__device__ __forceinline__ void gl16(const void* g, void* l) {
    __builtin_amdgcn_global_load_lds(
        (const __attribute__((address_space(1))) unsigned int*)g,
        (__attribute__((address_space(3))) unsigned int*)l, 16, 0, 0);
}

template<int N> __device__ __forceinline__ void wait_vm() {
    if constexpr (N == 0)      asm volatile("s_waitcnt vmcnt(0)" ::: "memory");
    else if constexpr (N == 4) asm volatile("s_waitcnt vmcnt(4)" ::: "memory");
    else                       asm volatile("s_waitcnt vmcnt(8)" ::: "memory");
}
__device__ __forceinline__ void wait_lgkm0() {
    asm volatile("s_waitcnt lgkmcnt(0)" ::: "memory");
}
__device__ __forceinline__ void bar() { __builtin_amdgcn_s_barrier(); }
__device__ __forceinline__ void sbar0() { __builtin_amdgcn_sched_barrier(0); }

// ---------------- fused prep: rope tables + a/x hi-lo cast + 4 weight transpose-casts --
__global__ __launch_bounds__(256) void prep_k(
    const float* __restrict__ a, const float* __restrict__ x,
    const float* __restrict__ Wq, const float* __restrict__ Wk,
    const float* __restrict__ Wv, const float* __restrict__ Wo,
    float* __restrict__ cosT, float* __restrict__ sinT,
    unsigned short* __restrict__ ahi, unsigned short* __restrict__ alo,
    unsigned short* __restrict__ xhi, unsigned short* __restrict__ xlo,
    unsigned short* __restrict__ Wqth, unsigned short* __restrict__ Wqtl,
    unsigned short* __restrict__ Wkth, unsigned short* __restrict__ Wktl,
    unsigned short* __restrict__ Wvth, unsigned short* __restrict__ Woth)
{
    __shared__ float tile[64][65];
    int bid = blockIdx.x;
    int tid = threadIdx.x;
    if (bid < 2048) {
        int t = bid;
        float ex   = (float)tid / (float)HALF_;
        float invf = 1.0f / powf(10000.0f, ex);
        float ang  = (float)t * invf;
        float sv, cv;
        sincosf(ang, &sv, &cv);
        cosT[t*HALF_ + tid] = cv;
        sinT[t*HALF_ + tid] = sv;
        return;
    }
    if (bid < 6144) {
        int i = (bid - 2048) * 256 + tid;
        const float* src; unsigned short *hi, *lo;
        if (i < 524288) { src = a; hi = ahi; lo = alo; }
        else { i -= 524288; src = x; hi = xhi; lo = xlo; }
        float4 v = ((const float4*)src)[i];
        ushort4 h, l;
        h.x = f2bf(v.x); l.x = f2bf(v.x - bf2f(h.x));
        h.y = f2bf(v.y); l.y = f2bf(v.y - bf2f(h.y));
        h.z = f2bf(v.z); l.z = f2bf(v.z - bf2f(h.z));
        h.w = f2bf(v.w); l.w = f2bf(v.w - bf2f(h.w));
        ((ushort4*)hi)[i] = h;
        ((ushort4*)lo)[i] = l;
        return;
    }
    const float* W; unsigned short *Whi, *Wlo; int N, blk; int wantLo;
    if (bid < 6400)      { W = Wq; Whi = Wqth; Wlo = Wqtl; N = 2048; blk = bid - 6144; wantLo = 1; }
    else if (bid < 6464) { W = Wk; Whi = Wkth; Wlo = Wktl; N = 512;  blk = bid - 6400; wantLo = 1; }
    else if (bid < 6720) { W = Wv; Whi = Wvth; Wlo = nullptr; N = 2048; blk = bid - 6464; wantLo = 0; }
    else                 { W = Wo; Whi = Woth; Wlo = nullptr; N = 512;  blk = bid - 6720; wantLo = 0; }
    int K = 512;
    int nbt = N >> 6;
    int nb = blk % nbt, kb = blk / nbt;
    int ty = tid >> 6, tx = tid & 63;
    for (int i = ty; i < 64; i += 4)
        tile[i][tx] = W[(size_t)(kb*64 + i) * N + nb*64 + tx];
    __syncthreads();
    for (int j = ty; j < 64; j += 4) {
        float v = tile[tx][j];
        unsigned short h = f2bf(v);
        size_t o = (size_t)(nb*64 + j) * K + kb*64 + tx;
        Whi[o] = h;
        if (wantLo) Wlo[o] = f2bf(v - bf2f(h));
    }
}

// ---------------- unified input-GEMM kernel: Q(split) + K(split) + V(plain,transposed) -
// grid 1152 = 8*144 XCD-chunked. sb<512: Qf = a@Wq (split). sb<640: Kf = x@Wk (split).
// else: Vt = bf16(a@Wv) transposed. 128x128 tile, BK=32, counted-vmcnt pipeline,
// interleaved [A|B] 128B rows, slot = g ^ (row&7).
__global__ __launch_bounds__(256, 2) void mm3_k(
    const unsigned short* __restrict__ ahi, const unsigned short* __restrict__ alo,
    const unsigned short* __restrict__ xhi, const unsigned short* __restrict__ xlo,
    const unsigned short* __restrict__ Wqth, const unsigned short* __restrict__ Wqtl,
    const unsigned short* __restrict__ Wkth, const unsigned short* __restrict__ Wktl,
    const unsigned short* __restrict__ Wvth,
    float* __restrict__ Qf, float* __restrict__ Kf, unsigned short* __restrict__ Vt)
{
    __shared__ __align__(16) short smem[2 * 16384];
    const int K = 512;

    int tid = threadIdx.x;
    int w = tid >> 6, l = tid & 63;
    int wm = w >> 1, wn = w & 1;
    int llo = l & 15, lhi = l >> 4;
    int rl8 = l >> 3, sl8 = l & 7;
    int bid = blockIdx.x;
    int sb = (bid & 7) * 144 + (bid >> 3);

    int split, vmode, idx, N;
    const unsigned short *pAhi, *pAlo = nullptr, *pBhi, *pBlo = nullptr;
    float* Cf = nullptr;
    if (sb < 512)      { pAhi = ahi; pAlo = alo; pBhi = Wqth; pBlo = Wqtl; Cf = Qf; N = 2048; idx = sb;       split = 1; vmode = 0; }
    else if (sb < 640) { pAhi = xhi; pAlo = xlo; pBhi = Wkth; pBlo = Wktl; Cf = Kf; N = 512;  idx = sb - 512; split = 1; vmode = 0; }
    else               { pAhi = ahi; pBhi = Wvth;                          N = 2048; idx = sb - 640;          split = 0; vmode = 1; }
    int nbt = N >> 7;
    int bx = idx % nbt, by = idx / nbt;
    int m0 = by << 7, n0 = bx << 7;

    const unsigned short* hs[4];
    const unsigned short* ls[4];
    int dst_[4];
    #pragma unroll
    for (int c = 0; c < 4; c++) {
        int r = (w << 5) + (c << 3) + rl8;
        int sp = sl8 ^ (r & 7);
        size_t off = (sp < 4) ? ((size_t)(m0 + r) * K + (sp << 3))
                              : ((size_t)(n0 + r) * K + ((sp - 4) << 3));
        hs[c] = (sp < 4 ? pAhi : pBhi) + off;
        if (split) ls[c] = (sp < 4 ? pAlo : pBlo) + off;
        dst_[c] = (w << 11) + (c << 9);
    }
    auto STAGE = [&](int cur, int k0) {
        short* base = smem + (cur << 14);
        #pragma unroll
        for (int c = 0; c < 4; c++) {
            gl16(hs[c] + k0, base + dst_[c]);
            if (split) gl16(ls[c] + k0, base + 8192 + dst_[c]);
        }
    };

    f32x4 acc[4][4];
    #pragma unroll
    for (int mi = 0; mi < 4; mi++)
        #pragma unroll
        for (int ni = 0; ni < 4; ni++) acc[mi][ni] = (f32x4){0.f,0.f,0.f,0.f};

    STAGE(0, 0);
    int cur = 0;
    for (int k = 0; k < 16; k++) {
        if (k + 1 < 16) {
            STAGE(cur ^ 1, (k + 1) << 5);
            if (split) wait_vm<8>(); else wait_vm<4>();
        } else wait_vm<0>();
        bar(); sbar0();
        short* Mh = smem + (cur << 14);
        short* Ml = Mh + 8192;
        s16x8 bh[4], bl[4];
        #pragma unroll
        for (int ni = 0; ni < 4; ni++) {
            int br = (wn << 6) + (ni << 4) + llo;
            int bo = (br << 6) + (((lhi | 4) ^ (br & 7)) << 3);
            bh[ni] = *(const s16x8*)&Mh[bo];
            if (split) bl[ni] = *(const s16x8*)&Ml[bo];
        }
        #pragma unroll
        for (int mi = 0; mi < 4; mi++) {
            int ar = (wm << 6) + (mi << 4) + llo;
            int ao = (ar << 6) + ((lhi ^ (ar & 7)) << 3);
            s16x8 ah = *(const s16x8*)&Mh[ao];
            s16x8 al;
            if (split) al = *(const s16x8*)&Ml[ao];
            #pragma unroll
            for (int ni = 0; ni < 4; ni++) {
                acc[mi][ni] = __builtin_amdgcn_mfma_f32_16x16x32_bf16(ah, bh[ni], acc[mi][ni], 0, 0, 0);
                if (split) {
                    acc[mi][ni] = __builtin_amdgcn_mfma_f32_16x16x32_bf16(ah, bl[ni], acc[mi][ni], 0, 0, 0);
                    acc[mi][ni] = __builtin_amdgcn_mfma_f32_16x16x32_bf16(al, bh[ni], acc[mi][ni], 0, 0, 0);
                }
            }
        }
        wait_lgkm0(); sbar0(); bar();
        cur ^= 1;
    }
    if (vmode) {
        #pragma unroll
        for (int mi = 0; mi < 4; mi++) {
            int row0 = m0 + (wm << 6) + (mi << 4) + (lhi << 2);
            int b = row0 >> 11, t = row0 & (T_ - 1);
            #pragma unroll
            for (int ni = 0; ni < 4; ni++) {
                int col = n0 + (wn << 6) + (ni << 4) + llo;
                f32x4 v = acc[mi][ni];
                ushort4 o;
                o.x = f2bf(v[0]); o.y = f2bf(v[1]); o.z = f2bf(v[2]); o.w = f2bf(v[3]);
                *(ushort4*)(Vt + ((size_t)(b*(NB_*C_) + col)) * T_ + t) = o;
            }
        }
    } else {
        #pragma unroll
        for (int mi = 0; mi < 4; mi++) {
            int row0 = m0 + (wm << 6) + (mi << 4) + (lhi << 2);
            #pragma unroll
            for (int ni = 0; ni < 4; ni++) {
                int col = n0 + (wn << 6) + (ni << 4) + llo;
                f32x4 v = acc[mi][ni];
                #pragma unroll
                for (int r = 0; r < 4; r++)
                    Cf[(size_t)(row0 + r) * N + col] = v[r];
            }
        }
    }
}

// ---------------- output GEMM (plain bf16 -> fp32): 128x128, BK=32 ----------------
__global__ __launch_bounds__(256, 4) void mm_o_k(
    const unsigned short* __restrict__ Ahi,
    const unsigned short* __restrict__ Bhi,
    float* __restrict__ C, int M, int N, int K)
{
    __shared__ __align__(16) short smem[2 * 8192];
    int tid = threadIdx.x;
    int w = tid >> 6, l = tid & 63;
    int wm = w >> 1, wn = w & 1;
    int llo = l & 15, lhi = l >> 4;
    int rl8 = l >> 3, sl8 = l & 7;
    int nwg = gridDim.x;
    int bid = blockIdx.x;
    int sb = (bid & 7) * (nwg >> 3) + (bid >> 3);
    int nbt = N >> 7;
    int bx = sb % nbt, by = sb / nbt;
    int m0 = by << 7, n0 = bx << 7;

    const unsigned short* hs[4];
    int dst_[4];
    #pragma unroll
    for (int c = 0; c < 4; c++) {
        int r = (w << 5) + (c << 3) + rl8;
        int sp = sl8 ^ (r & 7);
        size_t off = (sp < 4) ? ((size_t)(m0 + r) * K + (sp << 3))
                              : ((size_t)(n0 + r) * K + ((sp - 4) << 3));
        hs[c] = (sp < 4 ? Ahi : Bhi) + off;
        dst_[c] = (w << 11) + (c << 9);
    }
    auto STAGE = [&](int cur, int k0) {
        short* base = smem + cur * 8192;
        #pragma unroll
        for (int c = 0; c < 4; c++) gl16(hs[c] + k0, base + dst_[c]);
    };

    f32x4 acc[4][4];
    #pragma unroll
    for (int mi = 0; mi < 4; mi++)
        #pragma unroll
        for (int ni = 0; ni < 4; ni++) acc[mi][ni] = (f32x4){0.f,0.f,0.f,0.f};

    const int NK = K >> 5;
    STAGE(0, 0);
    int cur = 0;
    for (int k = 0; k < NK; k++) {
        if (k + 1 < NK) { STAGE(cur ^ 1, (k + 1) << 5); wait_vm<4>(); }
        else wait_vm<0>();
        bar(); sbar0();
        short* Mh = smem + cur * 8192;
        s16x8 bh[4];
        #pragma unroll
        for (int ni = 0; ni < 4; ni++) {
            int br = (wn << 6) + (ni << 4) + llo;
            bh[ni] = *(const s16x8*)&Mh[(br << 6) + (((lhi | 4) ^ (br & 7)) << 3)];
        }
        #pragma unroll
        for (int mi = 0; mi < 4; mi++) {
            int ar = (wm << 6) + (mi << 4) + llo;
            s16x8 ah = *(const s16x8*)&Mh[(ar << 6) + ((lhi ^ (ar & 7)) << 3)];
            #pragma unroll
            for (int ni = 0; ni < 4; ni++)
                acc[mi][ni] = __builtin_amdgcn_mfma_f32_16x16x32_bf16(ah, bh[ni], acc[mi][ni], 0, 0, 0);
        }
        wait_lgkm0(); sbar0(); bar();
        cur ^= 1;
    }
    #pragma unroll
    for (int mi = 0; mi < 4; mi++) {
        int row0 = m0 + (wm << 6) + (mi << 4) + (lhi << 2);
        #pragma unroll
        for (int ni = 0; ni < 4; ni++) {
            int col = n0 + (wn << 6) + (ni << 4) + llo;
            f32x4 v = acc[mi][ni];
            #pragma unroll
            for (int r = 0; r < 4; r++)
                C[(size_t)(row0 + r) * N + col] = v[r];
        }
    }
}

// ---------------- fused Q RMSNorm+RoPE and K RoPE -> hi/lo bf16 ----------------
__global__ __launch_bounds__(256) void qk_post_k(
    const float* __restrict__ Qf, const float* __restrict__ Kf,
    const float* __restrict__ cosT, const float* __restrict__ sinT,
    unsigned short* __restrict__ Qhi, unsigned short* __restrict__ Qlo,
    unsigned short* __restrict__ Khi, unsigned short* __restrict__ Klo)
{
    int bid = blockIdx.x;
    if (bid < 4096) {
        int bt = bid;
        int t  = bt & (T_ - 1);
        int w = threadIdx.x >> 6, l = threadIdx.x & 63;
        const float* row = Qf + (size_t)bt * (NB_*C_) + (w << 9);
        int i0 = l << 2;
        float4 x1 = *(const float4*)(row + i0);
        float4 x2 = *(const float4*)(row + i0 + HALF_);
        float s = x1.x*x1.x + x1.y*x1.y + x1.z*x1.z + x1.w*x1.w
                + x2.x*x2.x + x2.y*x2.y + x2.z*x2.z + x2.w*x2.w;
        #pragma unroll
        for (int mask = 1; mask <= 32; mask <<= 1) s += __shfl_xor(s, mask, 64);
        float r = rsqrtf(s * (1.0f / (float)C_) + EPS_);
        float4 cv = *(const float4*)(cosT + t*HALF_ + i0);
        float4 sv = *(const float4*)(sinT + t*HALF_ + i0);
        float v1[4], v2[4];
        v1[0] = x1.x*r*cv.x - x2.x*r*sv.x;  v2[0] = x2.x*r*cv.x + x1.x*r*sv.x;
        v1[1] = x1.y*r*cv.y - x2.y*r*sv.y;  v2[1] = x2.y*r*cv.y + x1.y*r*sv.y;
        v1[2] = x1.z*r*cv.z - x2.z*r*sv.z;  v2[2] = x2.z*r*cv.z + x1.z*r*sv.z;
        v1[3] = x1.w*r*cv.w - x2.w*r*sv.w;  v2[3] = x2.w*r*cv.w + x1.w*r*sv.w;
        size_t o = (size_t)bt * (NB_*C_) + (w << 9) + i0;
        ushort4 h1, h2, l1, l2;
        h1.x = f2bf(v1[0]); l1.x = f2bf(v1[0] - bf2f(h1.x));
        h1.y = f2bf(v1[1]); l1.y = f2bf(v1[1] - bf2f(h1.y));
        h1.z = f2bf(v1[2]); l1.z = f2bf(v1[2] - bf2f(h1.z));
        h1.w = f2bf(v1[3]); l1.w = f2bf(v1[3] - bf2f(h1.w));
        h2.x = f2bf(v2[0]); l2.x = f2bf(v2[0] - bf2f(h2.x));
        h2.y = f2bf(v2[1]); l2.y = f2bf(v2[1] - bf2f(h2.y));
        h2.z = f2bf(v2[2]); l2.z = f2bf(v2[2] - bf2f(h2.z));
        h2.w = f2bf(v2[3]); l2.w = f2bf(v2[3] - bf2f(h2.w));
        *(ushort4*)(Qhi + o)          = h1;
        *(ushort4*)(Qhi + o + HALF_)  = h2;
        *(ushort4*)(Qlo + o)          = l1;
        *(ushort4*)(Qlo + o + HALF_)  = l2;
        return;
    }
    int sub = threadIdx.x >> 7, l = threadIdx.x & 127;
    int bt = (bid - 4096) * 2 + sub;
    int t  = bt & (T_ - 1);
    const float* row = Kf + (size_t)bt * C_;
    int i0 = l << 1;
    float2 x1 = *(const float2*)(row + i0);
    float2 x2 = *(const float2*)(row + i0 + HALF_);
    float2 cv = *(const float2*)(cosT + t*HALF_ + i0);
    float2 sv = *(const float2*)(sinT + t*HALF_ + i0);
    float v1x = x1.x*cv.x - x2.x*sv.x, v2x = x2.x*cv.x + x1.x*sv.x;
    float v1y = x1.y*cv.y - x2.y*sv.y, v2y = x2.y*cv.y + x1.y*sv.y;
    size_t o = (size_t)bt * C_ + i0;
    ushort2 h1, h2, l1, l2;
    h1.x = f2bf(v1x); l1.x = f2bf(v1x - bf2f(h1.x));
    h1.y = f2bf(v1y); l1.y = f2bf(v1y - bf2f(h1.y));
    h2.x = f2bf(v2x); l2.x = f2bf(v2x - bf2f(h2.x));
    h2.y = f2bf(v2y); l2.y = f2bf(v2y - bf2f(h2.y));
    *(ushort2*)(Khi + o)         = h1;
    *(ushort2*)(Khi + o + HALF_) = h2;
    *(ushort2*)(Klo + o)         = l1;
    *(ushort2*)(Klo + o + HALF_) = l2;
}

// ---------------- QK + routing pass (compact triangle grid, interleaved rows) --------
__global__ __launch_bounds__(256, 2) void qk_routing_k(
    const unsigned short* __restrict__ Qhi, const unsigned short* __restrict__ Qlo,
    const unsigned short* __restrict__ Khi, const unsigned short* __restrict__ Klo,
    unsigned short* __restrict__ P, float* __restrict__ partS, unsigned* __restrict__ partA)
{
    __shared__ __align__(16) short smem[32768];

    int tid = threadIdx.x;
    int w = tid >> 6, l = tid & 63;
    int wm = w >> 1, wn = w & 1;
    int llo = l & 15, lhi = l >> 4;
    int rl8 = l >> 3, sl8 = l & 7;

    int bid = blockIdx.x;
    int j = (bid & 7) * 136 + (bid >> 3);
    int b = (j >= 544) ? 1 : 0;
    int j2 = j - 544 * b;
    int q = (int)((sqrtf(1.0f + 2.0f*(float)j2) - 1.0f) * 0.5f);
    if (2*(q+1)*(q+2) <= j2) q++;
    if (2*q*(q+1) > j2) q--;
    int r0 = j2 - 2*q*(q+1);
    int tloc = r0 / (q+1);
    int st = r0 - tloc*(q+1);
    int tt = (q << 2) + tloc;
    int t0 = tt << 5, s0 = st << 7;

    const unsigned short* hsrc[4];
    const unsigned short* lsrc[4];
    int dst_[4];
    #pragma unroll
    for (int c = 0; c < 4; c++) {
        int r = (w << 5) + (c << 3) + rl8;
        int sp = sl8 ^ (r & 7);
        size_t off = (sp < 4)
            ? ((size_t)(b*T_ + t0 + (r >> 2)) * (NB_*C_) + ((r & 3) << 9) + (sp << 3))
            : ((size_t)(b*T_ + s0 + r) * C_ + ((sp - 4) << 3));
        hsrc[c] = (sp < 4 ? Qhi : Khi) + off;
        lsrc[c] = (sp < 4 ? Qlo : Klo) + off;
        dst_[c] = (w << 11) + (c << 9);
    }
    auto STAGE = [&](int cur, int k0) {
        short* base = smem + (cur << 14);
        #pragma unroll
        for (int c = 0; c < 4; c++) {
            gl16(hsrc[c] + k0, base + dst_[c]);
            gl16(lsrc[c] + k0, base + 8192 + dst_[c]);
        }
    };

    f32x4 acc[4][4];
    #pragma unroll
    for (int mi = 0; mi < 4; mi++)
        #pragma unroll
        for (int ni = 0; ni < 4; ni++) acc[mi][ni] = (f32x4){0.f,0.f,0.f,0.f};

    STAGE(0, 0);
    int cur = 0;
    for (int k = 0; k < 16; k++) {
        if (k + 1 < 16) { STAGE(cur ^ 1, (k + 1) << 5); wait_vm<8>(); }
        else wait_vm<0>();
        bar(); sbar0();
        short* Mh = smem + (cur << 14);
        short* Ml = Mh + 8192;
        s16x8 bh[4], bl[4];
        #pragma unroll
        for (int ni = 0; ni < 4; ni++) {
            int br = (wn << 6) + (ni << 4) + llo;
            int bo = (br << 6) + (((lhi | 4) ^ (br & 7)) << 3);
            bh[ni] = *(const s16x8*)&Mh[bo];
            bl[ni] = *(const s16x8*)&Ml[bo];
        }
        #pragma unroll
        for (int mi = 0; mi < 4; mi++) {
            int ar = (wm << 6) + (mi << 4) + llo;
            int ao = (ar << 6) + ((lhi ^ (ar & 7)) << 3);
            s16x8 ah = *(const s16x8*)&Mh[ao];
            s16x8 al = *(const s16x8*)&Ml[ao];
            #pragma unroll
            for (int ni = 0; ni < 4; ni++) {
                acc[mi][ni] = __builtin_amdgcn_mfma_f32_16x16x32_bf16(ah, bh[ni], acc[mi][ni], 0, 0, 0);
                acc[mi][ni] = __builtin_amdgcn_mfma_f32_16x16x32_bf16(ah, bl[ni], acc[mi][ni], 0, 0, 0);
                acc[mi][ni] = __builtin_amdgcn_mfma_f32_16x16x32_bf16(al, bh[ni], acc[mi][ni], 0, 0, 0);
            }
        }
        wait_lgkm0(); sbar0(); bar();
        cur ^= 1;
    }
    __syncthreads();

    short* Pl = smem;
    #pragma unroll
    for (int mi = 0; mi < 4; mi++) {
        int tl = (wm << 4) + (mi << 2) + lhi;
        int tg = t0 + tl;
        float wsum = 0.f; unsigned ab = 0u;
        #pragma unroll
        for (int ni = 0; ni < 4; ni++) {
            int sl = (wn << 6) + (ni << 4) + llo;
            int sg = s0 + sl;
            f32x4 v = acc[mi][ni];
            float wu = 0.f; unsigned bits = 0u;
            if (sg <= tg) {
                float a0 = v[0]*RSC_, a1 = v[1]*RSC_, a2 = v[2]*RSC_, a3 = v[3]*RSC_;
                float m = fmaxf(fmaxf(a0, a1), fmaxf(a2, a3));
                bits = (a0 == m ? 1u : 0u) | (a1 == m ? 2u : 0u)
                     | (a2 == m ? 4u : 0u) | (a3 == m ? 8u : 0u);
                wu = fmaxf(m, 0.f) + log1pf(expf(-fabsf(m)));
                wsum += wu; ab |= bits;
            }
            unsigned short wub = f2bf(wu);
            Pl[(0*32 + tl)*136 + sl] = (bits & 1u) ? (short)wub : (short)0;
            Pl[(1*32 + tl)*136 + sl] = (bits & 2u) ? (short)wub : (short)0;
            Pl[(2*32 + tl)*136 + sl] = (bits & 4u) ? (short)wub : (short)0;
            Pl[(3*32 + tl)*136 + sl] = (bits & 8u) ? (short)wub : (short)0;
        }
        #pragma unroll
        for (int mask = 1; mask <= 8; mask <<= 1) wsum += __shfl_xor(wsum, mask, 64);
        int ai = (int)ab;
        #pragma unroll
        for (int mask = 1; mask <= 8; mask <<= 1) ai |= __shfl_xor(ai, mask, 64);
        if (llo == 0) {
            size_t pidx = ((((size_t)(b*64 + tt) * 16 + st) * 2 + wn) * 32) + tl;
            partS[pidx] = wsum;
            partA[pidx] = (unsigned)ai;
        }
    }
    __syncthreads();
    for (int i = tid; i < 2048; i += 256) {
        int row = i >> 4, g8 = i & 15;
        int n = row >> 5, tl = row & 31;
        u16x8 v = *(const u16x8*)&Pl[row*136 + (g8 << 3)];
        *(u16x8*)(P + ((size_t)((b*4 + n)*T_ + t0 + tl)) * T_ + s0 + (g8 << 3)) = v;
    }
}

// ---------------- PV pass: counted pipeline, bf16 partials, 4 blocks/CU ----------------
__global__ __launch_bounds__(256, 4) void pv_k(
    const unsigned short* __restrict__ P, const unsigned short* __restrict__ Vt,
    unsigned short* __restrict__ py)
{
    __shared__ __align__(16) short smem[32768];
    int tid = threadIdx.x;
    int w = tid >> 6, l = tid & 63;
    int wm = w >> 1, wn = w & 1;
    int llo = l & 15, lhi = l >> 4;
    int rl = l >> 3, gs8 = l & 7;
    int rb = w << 5;
    int bid = blockIdx.x;
    int ph = bid & 3, cc = (bid >> 2) & 3, tt = 15 - ((bid >> 4) & 15), b = bid >> 8;
    int t0 = tt << 7, c0 = cc << 7;
    int b4 = b * 4;
    size_t bV = (size_t)b * (NB_*C_);

    size_t pa_[4], pb_[4];
    int dsb_[4];
    #pragma unroll
    for (int i8 = 0; i8 < 4; i8++) {
        int r = rb + (i8 << 3) + rl;
        int sg = (gs8 ^ (r & 7)) << 3;
        pa_[i8] = (size_t)(t0 + r) * T_ + sg;
        pb_[i8] = (size_t)(c0 + r) * T_ + sg;
        dsb_[i8] = (rb + (i8 << 3)) << 6;
    }
    auto STAGE = [&](int cur, int n, int k0) {
        short* base = smem + (cur << 14);
        size_t na = (size_t)(b4 + n) * T_ * T_;
        size_t nb = (bV + (size_t)(n << 9)) * T_;
        #pragma unroll
        for (int i8 = 0; i8 < 4; i8++) {
            gl16(P  + na + pa_[i8] + k0, base + dsb_[i8]);
            gl16(Vt + nb + pb_[i8] + k0, base + 8192 + dsb_[i8]);
        }
    };

    f32x4 acc[4][4];
    #pragma unroll
    for (int mi = 0; mi < 4; mi++)
        #pragma unroll
        for (int ni = 0; ni < 4; ni++) acc[mi][ni] = (f32x4){0.f,0.f,0.f,0.f};

    int first_sb = ph << 7;
    int num_sb = (first_sb <= t0 + 127) ? (((t0 + 127 - first_sb) >> 9) + 1) : 0;
    int nsteps = num_sb << 3;

    if (nsteps > 0) {
        int n_p = 0, sb_p = first_sb, h_p = 0;
        auto ADV = [&]() {
            h_p ^= 1;
            if (!h_p) { sb_p += 512; if (sb_p > t0 + 127) { sb_p = first_sb; n_p++; } }
        };
        STAGE(0, n_p, sb_p + (h_p << 6)); ADV();
        int cur = 0;
        for (int s = 0; s < nsteps; s++) {
            if (s + 1 < nsteps) { STAGE(cur ^ 1, n_p, sb_p + (h_p << 6)); ADV(); wait_vm<8>(); }
            else wait_vm<0>();
            bar(); sbar0();
            short* Ah = smem + (cur << 14);
            short* Bh = Ah + 8192;
            #pragma unroll
            for (int ks = 0; ks < 2; ks++) {
                s16x8 bh[4];
                #pragma unroll
                for (int ni = 0; ni < 4; ni++) {
                    int br = (wn << 6) + (ni << 4) + llo;
                    bh[ni] = *(const s16x8*)&Bh[br*64 + ((((ks << 2) + lhi) ^ (br & 7)) << 3)];
                }
                #pragma unroll
                for (int mi = 0; mi < 4; mi++) {
                    int ar = (wm << 6) + (mi << 4) + llo;
                    s16x8 ah = *(const s16x8*)&Ah[ar*64 + ((((ks << 2) + lhi) ^ (ar & 7)) << 3)];
                    #pragma unroll
                    for (int ni = 0; ni < 4; ni++)
                        acc[mi][ni] = __builtin_amdgcn_mfma_f32_16x16x32_bf16(ah, bh[ni], acc[mi][ni], 0, 0, 0);
                }
            }
            wait_lgkm0(); sbar0(); bar();
            cur ^= 1;
        }
    }
    unsigned short* out = py + (size_t)ph * (BT_*(size_t)C_);
    #pragma unroll
    for (int mi = 0; mi < 4; mi++) {
        int row0 = t0 + (wm << 6) + (mi << 4) + (lhi << 2);
        #pragma unroll
        for (int ni = 0; ni < 4; ni++) {
            int col = c0 + (wn << 6) + (ni << 4) + llo;
            f32x4 v = acc[mi][ni];
            #pragma unroll
            for (int r = 0; r < 4; r++)
                out[(size_t)(b*T_ + row0 + r) * C_ + col] = f2bf(v[r]);
        }
    }
}

// ---------------- combine: bf16 y partials + S/act + sinks -> ybf16 ----------------
__global__ __launch_bounds__(256) void combine3_k(
    const unsigned short* __restrict__ py, const float* __restrict__ partS,
    const unsigned* __restrict__ partA,
    const float* __restrict__ basis, const float* __restrict__ resid_sink,
    unsigned short* __restrict__ ybf)
{
    int bt = blockIdx.x;
    int t = bt & (T_ - 1);
    int b = bt >> 11;
    int i = threadIdx.x;
    int tt32 = t >> 5, tl = t & 31;
    int stmax = tt32 >> 2;
    float S = 0.f; unsigned act = 0u;
    for (int st = 0; st <= stmax; st++) {
        #pragma unroll
        for (int wn = 0; wn < 2; wn++) {
            size_t idx = ((((size_t)(b*64 + tt32) * 16 + st) * 2 + wn) * 32) + tl;
            S += partS[idx];
            act |= partA[idx];
        }
    }
    float y0 = 0.f, y1 = 0.f;
    #pragma unroll
    for (int ph = 0; ph < 4; ph++) {
        y0 += bf2f(py[(size_t)ph * (BT_*(size_t)C_) + (size_t)bt * C_ + i]);
        y1 += bf2f(py[(size_t)ph * (BT_*(size_t)C_) + (size_t)bt * C_ + i + 256]);
    }
    float scale = fminf(1.0f / (S + 1e-6f), 1.0f);
    float residual = 1.0f - scale * S;
    if (t < T_ - 1) act = 0xFu;
    float o0 = scale * y0, o1 = scale * y1;
    #pragma unroll
    for (int n = 0; n < 4; n++) if ((act >> n) & 1u) {
        o0 += basis[n*C_ + i];
        o1 += basis[n*C_ + i + 256];
    }
    o0 += residual * resid_sink[i];
    o1 += residual * resid_sink[i + 256];
    ybf[(size_t)bt * C_ + i]       = f2bf(o0);
    ybf[(size_t)bt * C_ + i + 256] = f2bf(o1);
}

extern "C" void kernel_launch(void* const* d_in, const int* in_sizes, int n_in,
                              void* d_out, int out_size, void* d_ws, size_t ws_size,
                              hipStream_t stream) {
    const float* a    = (const float*)d_in[0];
    const float* x    = (const float*)d_in[1];
    const float* Wq   = (const float*)d_in[2];
    const float* Wk   = (const float*)d_in[3];
    const float* Wv   = (const float*)d_in[4];
    const float* Wo   = (const float*)d_in[5];
    const float* vres = (const float*)d_in[6];
    const float* vbas = (const float*)d_in[7];

    float* ws = (float*)d_ws;
    float* cosT = ws;                              // 524288 f
    float* sinT = cosT + 524288;                   // 524288 f
    float* Qf   = sinT + 524288;                   // 8388608 f (reused as py bf16)
    float* Kf   = Qf + 8388608;                    // 2097152 f (reused: partS/partA/ybf)
    unsigned short* ahi  = (unsigned short*)(Kf + 2097152);
    unsigned short* alo  = ahi  + 2097152;
    unsigned short* xhi  = alo  + 2097152;
    unsigned short* xlo  = xhi  + 2097152;
    unsigned short* Wqth = xlo  + 2097152;
    unsigned short* Wqtl = Wqth + 1048576;
    unsigned short* Wkth = Wqtl + 1048576;
    unsigned short* Wktl = Wkth + 262144;
    unsigned short* Wvth = Wktl + 262144;
    unsigned short* Woth = Wvth + 1048576;
    unsigned short* Qhi  = Woth + 262144;
    unsigned short* Qlo  = Qhi  + 8388608;
    unsigned short* Khi  = Qlo  + 8388608;
    unsigned short* Klo  = Khi  + 2097152;
    unsigned short* Vt   = Klo  + 2097152;
    unsigned short* P    = Vt   + 8388608;         // 33554432 shorts

    unsigned short* py = (unsigned short*)Qf;      // Qf dead after qk_post
    float* partS = Kf;
    unsigned* partA = (unsigned*)(Kf + 131072);
    unsigned short* ybf = (unsigned short*)(Kf + 262144);

    prep_k<<<6784, 256, 0, stream>>>(a, x, Wq, Wk, Wv, Wo, cosT, sinT,
                                     ahi, alo, xhi, xlo,
                                     Wqth, Wqtl, Wkth, Wktl, Wvth, Woth);

    mm3_k<<<1152, 256, 0, stream>>>(ahi, alo, xhi, xlo,
                                    Wqth, Wqtl, Wkth, Wktl, Wvth,
                                    Qf, Kf, Vt);

    qk_post_k<<<6144, 256, 0, stream>>>(Qf, Kf, cosT, sinT, Qhi, Qlo, Khi, Klo);

    qk_routing_k<<<1088, 256, 0, stream>>>(Qhi, Qlo, Khi, Klo, P, partS, partA);
    pv_k<<<512, 256, 0, stream>>>(P, Vt, py);
    combine3_k<<<BT_, 256, 0, stream>>>(py, partS, partA, vbas, vres, ybf);

    mm_o_k<<<128, 256, 0, stream>>>(ybf, Woth, (float*)d_out, BT_, 512, 512);
}

// Round 14
// 217.872 us; speedup vs baseline: 1.0154x; 1.0154x over previous
//
#include <hip/hip_runtime.h>
#include <math.h>

#define B_    2
#define T_    2048
#define C_    512
#define NB_   4
#define HALF_ 256
#define BT_   (B_*T_)
#define EPS_  1.1920929e-07f
#define RSC_  0.044194173824159216f   // 1/sqrt(512)

using f32x4 = __attribute__((ext_vector_type(4))) float;
using s16x8 = __attribute__((ext_vector_type(8))) short;
using u16x8 = __attribute__((ext_vector_type(8))) unsigned short;

__device__ __forceinline__ unsigned short f2bf(float f) {
    unsigned x = __float_as_uint(f);
    unsigned r = (x + 0x7fffu + ((x >> 16) & 1u)) >> 16;
    return (unsigned short)r;
}
__device__ __forceinline__ float bf2f(unsigned short h) {
    return __uint_as_float(((unsigned)h) << 16);
}

// direct global->LDS 16B: per-lane global src, wave-uniform LDS base (+lane*16B in HW)
__device__ __forceinline__ void gl16(const void* g, void* l) {
    __builtin_amdgcn_global_load_lds(
        (const __attribute__((address_space(1))) unsigned int*)g,
        (__attribute__((address_space(3))) unsigned int*)l, 16, 0, 0);
}

template<int N> __device__ __forceinline__ void wait_vm() {
    if constexpr (N == 0)      asm volatile("s_waitcnt vmcnt(0)" ::: "memory");
    else if constexpr (N == 4) asm volatile("s_waitcnt vmcnt(4)" ::: "memory");
    else                       asm volatile("s_waitcnt vmcnt(8)" ::: "memory");
}
__device__ __forceinline__ void wait_lgkm0() {
    asm volatile("s_waitcnt lgkmcnt(0)" ::: "memory");
}
__device__ __forceinline__ void bar() { __builtin_amdgcn_s_barrier(); }
__device__ __forceinline__ void sbar0() { __builtin_amdgcn_sched_barrier(0); }

// ---------------- fused prep: rope tables + a/x hi-lo cast + 4 weight transpose-casts --
__global__ __launch_bounds__(256) void prep_k(
    const float* __restrict__ a, const float* __restrict__ x,
    const float* __restrict__ Wq, const float* __restrict__ Wk,
    const float* __restrict__ Wv, const float* __restrict__ Wo,
    float* __restrict__ cosT, float* __restrict__ sinT,
    unsigned short* __restrict__ ahi, unsigned short* __restrict__ alo,
    unsigned short* __restrict__ xhi, unsigned short* __restrict__ xlo,
    unsigned short* __restrict__ Wqth, unsigned short* __restrict__ Wqtl,
    unsigned short* __restrict__ Wkth, unsigned short* __restrict__ Wktl,
    unsigned short* __restrict__ Wvth, unsigned short* __restrict__ Woth)
{
    __shared__ float tile[64][65];
    int bid = blockIdx.x;
    int tid = threadIdx.x;
    if (bid < 2048) {
        int t = bid;
        float ex   = (float)tid / (float)HALF_;
        float invf = 1.0f / powf(10000.0f, ex);
        float ang  = (float)t * invf;
        float sv, cv;
        sincosf(ang, &sv, &cv);
        cosT[t*HALF_ + tid] = cv;
        sinT[t*HALF_ + tid] = sv;
        return;
    }
    if (bid < 6144) {
        int i = (bid - 2048) * 256 + tid;
        const float* src; unsigned short *hi, *lo;
        if (i < 524288) { src = a; hi = ahi; lo = alo; }
        else { i -= 524288; src = x; hi = xhi; lo = xlo; }
        float4 v = ((const float4*)src)[i];
        ushort4 h, l;
        h.x = f2bf(v.x); l.x = f2bf(v.x - bf2f(h.x));
        h.y = f2bf(v.y); l.y = f2bf(v.y - bf2f(h.y));
        h.z = f2bf(v.z); l.z = f2bf(v.z - bf2f(h.z));
        h.w = f2bf(v.w); l.w = f2bf(v.w - bf2f(h.w));
        ((ushort4*)hi)[i] = h;
        ((ushort4*)lo)[i] = l;
        return;
    }
    const float* W; unsigned short *Whi, *Wlo; int N, blk; int wantLo;
    if (bid < 6400)      { W = Wq; Whi = Wqth; Wlo = Wqtl; N = 2048; blk = bid - 6144; wantLo = 1; }
    else if (bid < 6464) { W = Wk; Whi = Wkth; Wlo = Wktl; N = 512;  blk = bid - 6400; wantLo = 1; }
    else if (bid < 6720) { W = Wv; Whi = Wvth; Wlo = nullptr; N = 2048; blk = bid - 6464; wantLo = 0; }
    else                 { W = Wo; Whi = Woth; Wlo = nullptr; N = 512;  blk = bid - 6720; wantLo = 0; }
    int K = 512;
    int nbt = N >> 6;
    int nb = blk % nbt, kb = blk / nbt;
    int ty = tid >> 6, tx = tid & 63;
    for (int i = ty; i < 64; i += 4)
        tile[i][tx] = W[(size_t)(kb*64 + i) * N + nb*64 + tx];
    __syncthreads();
    for (int j = ty; j < 64; j += 4) {
        float v = tile[tx][j];
        unsigned short h = f2bf(v);
        size_t o = (size_t)(nb*64 + j) * K + kb*64 + tx;
        Whi[o] = h;
        if (wantLo) Wlo[o] = f2bf(v - bf2f(h));
    }
}

// ---------------- generic MFMA GEMM: C[M][N] fp32 = A[M][K] @ Bt[N][K] ----------------
// 128x128 tile, BK=32, counted-vmcnt 2-deep pipeline.
// LDS: interleaved [A|B] rows of 128B (64 shorts), slot = g ^ (row&7).
template<int SPLIT>
__global__ __launch_bounds__(256, SPLIT ? 2 : 4) void mm_k(
    const unsigned short* __restrict__ Ahi, const unsigned short* __restrict__ Alo,
    const unsigned short* __restrict__ Bhi, const unsigned short* __restrict__ Blo,
    float* __restrict__ C, int M, int N, int K)
{
    constexpr int BUFS = SPLIT ? 16384 : 8192;   // shorts per buffer
    __shared__ __align__(16) short smem[2 * BUFS];

    int tid = threadIdx.x;
    int w = tid >> 6, l = tid & 63;
    int wm = w >> 1, wn = w & 1;
    int llo = l & 15, lhi = l >> 4;
    int rl8 = l >> 3, sl8 = l & 7;
    int nwg = gridDim.x;
    int bid = blockIdx.x;
    int sb = (bid & 7) * (nwg >> 3) + (bid >> 3);   // XCD-chunked (nwg%8==0)
    int nbt = N >> 7;
    int bx = sb % nbt, by = sb / nbt;
    int m0 = by << 7, n0 = bx << 7;

    const unsigned short* hs[4];
    const unsigned short* ls[4];
    int dst_[4];
    #pragma unroll
    for (int c = 0; c < 4; c++) {
        int r = (w << 5) + (c << 3) + rl8;
        int sp = sl8 ^ (r & 7);
        size_t off = (sp < 4) ? ((size_t)(m0 + r) * K + (sp << 3))
                              : ((size_t)(n0 + r) * K + ((sp - 4) << 3));
        hs[c] = (sp < 4 ? Ahi : Bhi) + off;
        if constexpr (SPLIT) ls[c] = (sp < 4 ? Alo : Blo) + off;
        dst_[c] = (w << 11) + (c << 9);   // shorts
    }
    auto STAGE = [&](int cur, int k0) {
        short* base = smem + cur * BUFS;
        #pragma unroll
        for (int c = 0; c < 4; c++) {
            gl16(hs[c] + k0, base + dst_[c]);
            if constexpr (SPLIT) gl16(ls[c] + k0, base + 8192 + dst_[c]);
        }
    };

    f32x4 acc[4][4];
    #pragma unroll
    for (int mi = 0; mi < 4; mi++)
        #pragma unroll
        for (int ni = 0; ni < 4; ni++) acc[mi][ni] = (f32x4){0.f,0.f,0.f,0.f};

    const int NK = K >> 5;
    STAGE(0, 0);
    int cur = 0;
    for (int k = 0; k < NK; k++) {
        if (k + 1 < NK) { STAGE(cur ^ 1, (k + 1) << 5); wait_vm<SPLIT ? 8 : 4>(); }
        else wait_vm<0>();
        bar(); sbar0();
        short* Mh = smem + cur * BUFS;
        short* Ml = Mh + 8192;
        s16x8 bh[4], bl[4];
        #pragma unroll
        for (int ni = 0; ni < 4; ni++) {
            int br = (wn << 6) + (ni << 4) + llo;
            int bo = (br << 6) + (((lhi | 4) ^ (br & 7)) << 3);
            bh[ni] = *(const s16x8*)&Mh[bo];
            if constexpr (SPLIT) bl[ni] = *(const s16x8*)&Ml[bo];
        }
        #pragma unroll
        for (int mi = 0; mi < 4; mi++) {
            int ar = (wm << 6) + (mi << 4) + llo;
            int ao = (ar << 6) + ((lhi ^ (ar & 7)) << 3);
            s16x8 ah = *(const s16x8*)&Mh[ao];
            s16x8 al;
            if constexpr (SPLIT) al = *(const s16x8*)&Ml[ao];
            #pragma unroll
            for (int ni = 0; ni < 4; ni++) {
                acc[mi][ni] = __builtin_amdgcn_mfma_f32_16x16x32_bf16(ah, bh[ni], acc[mi][ni], 0, 0, 0);
                if constexpr (SPLIT) {
                    acc[mi][ni] = __builtin_amdgcn_mfma_f32_16x16x32_bf16(ah, bl[ni], acc[mi][ni], 0, 0, 0);
                    acc[mi][ni] = __builtin_amdgcn_mfma_f32_16x16x32_bf16(al, bh[ni], acc[mi][ni], 0, 0, 0);
                }
            }
        }
        wait_lgkm0(); sbar0(); bar();
        cur ^= 1;
    }
    #pragma unroll
    for (int mi = 0; mi < 4; mi++) {
        int row0 = m0 + (wm << 6) + (mi << 4) + (lhi << 2);
        #pragma unroll
        for (int ni = 0; ni < 4; ni++) {
            int col = n0 + (wn << 6) + (ni << 4) + llo;
            f32x4 v = acc[mi][ni];
            #pragma unroll
            for (int r = 0; r < 4; r++)
                C[(size_t)(row0 + r) * N + col] = v[r];
        }
    }
}

// ---------------- V GEMM (plain bf16), interleaved rows, transposed-bf16 epilogue -----
__global__ __launch_bounds__(256, 4) void mm_v_k(
    const unsigned short* __restrict__ Ahi,
    const unsigned short* __restrict__ Bhi,
    unsigned short* __restrict__ Vt, int M, int N, int K)
{
    __shared__ __align__(16) short smem[2 * 8192];
    int tid = threadIdx.x;
    int w = tid >> 6, l = tid & 63;
    int wm = w >> 1, wn = w & 1;
    int llo = l & 15, lhi = l >> 4;
    int rl8 = l >> 3, sl8 = l & 7;
    int nwg = gridDim.x;
    int bid = blockIdx.x;
    int sb = (bid & 7) * (nwg >> 3) + (bid >> 3);
    int nbt = N >> 7;
    int bx = sb % nbt, by = sb / nbt;
    int m0 = by << 7, n0 = bx << 7;

    const unsigned short* hs[4];
    int dst_[4];
    #pragma unroll
    for (int c = 0; c < 4; c++) {
        int r = (w << 5) + (c << 3) + rl8;
        int sp = sl8 ^ (r & 7);
        size_t off = (sp < 4) ? ((size_t)(m0 + r) * K + (sp << 3))
                              : ((size_t)(n0 + r) * K + ((sp - 4) << 3));
        hs[c] = (sp < 4 ? Ahi : Bhi) + off;
        dst_[c] = (w << 11) + (c << 9);
    }
    auto STAGE = [&](int cur, int k0) {
        short* base = smem + cur * 8192;
        #pragma unroll
        for (int c = 0; c < 4; c++) gl16(hs[c] + k0, base + dst_[c]);
    };

    f32x4 acc[4][4];
    #pragma unroll
    for (int mi = 0; mi < 4; mi++)
        #pragma unroll
        for (int ni = 0; ni < 4; ni++) acc[mi][ni] = (f32x4){0.f,0.f,0.f,0.f};

    const int NK = K >> 5;
    STAGE(0, 0);
    int cur = 0;
    for (int k = 0; k < NK; k++) {
        if (k + 1 < NK) { STAGE(cur ^ 1, (k + 1) << 5); wait_vm<4>(); }
        else wait_vm<0>();
        bar(); sbar0();
        short* Mh = smem + cur * 8192;
        s16x8 bh[4];
        #pragma unroll
        for (int ni = 0; ni < 4; ni++) {
            int br = (wn << 6) + (ni << 4) + llo;
            bh[ni] = *(const s16x8*)&Mh[(br << 6) + (((lhi | 4) ^ (br & 7)) << 3)];
        }
        #pragma unroll
        for (int mi = 0; mi < 4; mi++) {
            int ar = (wm << 6) + (mi << 4) + llo;
            s16x8 ah = *(const s16x8*)&Mh[(ar << 6) + ((lhi ^ (ar & 7)) << 3)];
            #pragma unroll
            for (int ni = 0; ni < 4; ni++)
                acc[mi][ni] = __builtin_amdgcn_mfma_f32_16x16x32_bf16(ah, bh[ni], acc[mi][ni], 0, 0, 0);
        }
        wait_lgkm0(); sbar0(); bar();
        cur ^= 1;
    }
    #pragma unroll
    for (int mi = 0; mi < 4; mi++) {
        int row0 = m0 + (wm << 6) + (mi << 4) + (lhi << 2);
        int b = row0 >> 11, t = row0 & (T_ - 1);
        #pragma unroll
        for (int ni = 0; ni < 4; ni++) {
            int col = n0 + (wn << 6) + (ni << 4) + llo;
            f32x4 v = acc[mi][ni];
            ushort4 o;
            o.x = f2bf(v[0]); o.y = f2bf(v[1]); o.z = f2bf(v[2]); o.w = f2bf(v[3]);
            *(ushort4*)(Vt + ((size_t)(b*(NB_*C_) + col)) * T_ + t) = o;
        }
    }
}

// ---------------- fused Q RMSNorm+RoPE and K RoPE -> hi/lo bf16 ----------------
__global__ __launch_bounds__(256) void qk_post_k(
    const float* __restrict__ Qf, const float* __restrict__ Kf,
    const float* __restrict__ cosT, const float* __restrict__ sinT,
    unsigned short* __restrict__ Qhi, unsigned short* __restrict__ Qlo,
    unsigned short* __restrict__ Khi, unsigned short* __restrict__ Klo)
{
    int bid = blockIdx.x;
    if (bid < 4096) {
        int bt = bid;
        int t  = bt & (T_ - 1);
        int w = threadIdx.x >> 6, l = threadIdx.x & 63;
        const float* row = Qf + (size_t)bt * (NB_*C_) + (w << 9);
        int i0 = l << 2;
        float4 x1 = *(const float4*)(row + i0);
        float4 x2 = *(const float4*)(row + i0 + HALF_);
        float s = x1.x*x1.x + x1.y*x1.y + x1.z*x1.z + x1.w*x1.w
                + x2.x*x2.x + x2.y*x2.y + x2.z*x2.z + x2.w*x2.w;
        #pragma unroll
        for (int mask = 1; mask <= 32; mask <<= 1) s += __shfl_xor(s, mask, 64);
        float r = rsqrtf(s * (1.0f / (float)C_) + EPS_);
        float4 cv = *(const float4*)(cosT + t*HALF_ + i0);
        float4 sv = *(const float4*)(sinT + t*HALF_ + i0);
        float v1[4], v2[4];
        v1[0] = x1.x*r*cv.x - x2.x*r*sv.x;  v2[0] = x2.x*r*cv.x + x1.x*r*sv.x;
        v1[1] = x1.y*r*cv.y - x2.y*r*sv.y;  v2[1] = x2.y*r*cv.y + x1.y*r*sv.y;
        v1[2] = x1.z*r*cv.z - x2.z*r*sv.z;  v2[2] = x2.z*r*cv.z + x1.z*r*sv.z;
        v1[3] = x1.w*r*cv.w - x2.w*r*sv.w;  v2[3] = x2.w*r*cv.w + x1.w*r*sv.w;
        size_t o = (size_t)bt * (NB_*C_) + (w << 9) + i0;
        ushort4 h1, h2, l1, l2;
        h1.x = f2bf(v1[0]); l1.x = f2bf(v1[0] - bf2f(h1.x));
        h1.y = f2bf(v1[1]); l1.y = f2bf(v1[1] - bf2f(h1.y));
        h1.z = f2bf(v1[2]); l1.z = f2bf(v1[2] - bf2f(h1.z));
        h1.w = f2bf(v1[3]); l1.w = f2bf(v1[3] - bf2f(h1.w));
        h2.x = f2bf(v2[0]); l2.x = f2bf(v2[0] - bf2f(h2.x));
        h2.y = f2bf(v2[1]); l2.y = f2bf(v2[1] - bf2f(h2.y));
        h2.z = f2bf(v2[2]); l2.z = f2bf(v2[2] - bf2f(h2.z));
        h2.w = f2bf(v2[3]); l2.w = f2bf(v2[3] - bf2f(h2.w));
        *(ushort4*)(Qhi + o)          = h1;
        *(ushort4*)(Qhi + o + HALF_)  = h2;
        *(ushort4*)(Qlo + o)          = l1;
        *(ushort4*)(Qlo + o + HALF_)  = l2;
        return;
    }
    int sub = threadIdx.x >> 7, l = threadIdx.x & 127;
    int bt = (bid - 4096) * 2 + sub;
    int t  = bt & (T_ - 1);
    const float* row = Kf + (size_t)bt * C_;
    int i0 = l << 1;
    float2 x1 = *(const float2*)(row + i0);
    float2 x2 = *(const float2*)(row + i0 + HALF_);
    float2 cv = *(const float2*)(cosT + t*HALF_ + i0);
    float2 sv = *(const float2*)(sinT + t*HALF_ + i0);
    float v1x = x1.x*cv.x - x2.x*sv.x, v2x = x2.x*cv.x + x1.x*sv.x;
    float v1y = x1.y*cv.y - x2.y*sv.y, v2y = x2.y*cv.y + x1.y*sv.y;
    size_t o = (size_t)bt * C_ + i0;
    ushort2 h1, h2, l1, l2;
    h1.x = f2bf(v1x); l1.x = f2bf(v1x - bf2f(h1.x));
    h1.y = f2bf(v1y); l1.y = f2bf(v1y - bf2f(h1.y));
    h2.x = f2bf(v2x); l2.x = f2bf(v2x - bf2f(h2.x));
    h2.y = f2bf(v2y); l2.y = f2bf(v2y - bf2f(h2.y));
    *(ushort2*)(Khi + o)         = h1;
    *(ushort2*)(Khi + o + HALF_) = h2;
    *(ushort2*)(Klo + o)         = l1;
    *(ushort2*)(Klo + o + HALF_) = l2;
}

// ---------------- QK + routing pass (compact triangle grid, interleaved rows) --------
__global__ __launch_bounds__(256, 2) void qk_routing_k(
    const unsigned short* __restrict__ Qhi, const unsigned short* __restrict__ Qlo,
    const unsigned short* __restrict__ Khi, const unsigned short* __restrict__ Klo,
    unsigned short* __restrict__ P, float* __restrict__ partS, unsigned* __restrict__ partA)
{
    __shared__ __align__(16) short smem[32768];

    int tid = threadIdx.x;
    int w = tid >> 6, l = tid & 63;
    int wm = w >> 1, wn = w & 1;
    int llo = l & 15, lhi = l >> 4;
    int rl8 = l >> 3, sl8 = l & 7;

    int bid = blockIdx.x;
    int j = (bid & 7) * 136 + (bid >> 3);
    int b = (j >= 544) ? 1 : 0;
    int j2 = j - 544 * b;
    int q = (int)((sqrtf(1.0f + 2.0f*(float)j2) - 1.0f) * 0.5f);
    if (2*(q+1)*(q+2) <= j2) q++;
    if (2*q*(q+1) > j2) q--;
    int r0 = j2 - 2*q*(q+1);
    int tloc = r0 / (q+1);
    int st = r0 - tloc*(q+1);
    int tt = (q << 2) + tloc;
    int t0 = tt << 5, s0 = st << 7;

    const unsigned short* hsrc[4];
    const unsigned short* lsrc[4];
    int dst_[4];
    #pragma unroll
    for (int c = 0; c < 4; c++) {
        int r = (w << 5) + (c << 3) + rl8;
        int sp = sl8 ^ (r & 7);
        size_t off = (sp < 4)
            ? ((size_t)(b*T_ + t0 + (r >> 2)) * (NB_*C_) + ((r & 3) << 9) + (sp << 3))
            : ((size_t)(b*T_ + s0 + r) * C_ + ((sp - 4) << 3));
        hsrc[c] = (sp < 4 ? Qhi : Khi) + off;
        lsrc[c] = (sp < 4 ? Qlo : Klo) + off;
        dst_[c] = (w << 11) + (c << 9);
    }
    auto STAGE = [&](int cur, int k0) {
        short* base = smem + (cur << 14);
        #pragma unroll
        for (int c = 0; c < 4; c++) {
            gl16(hsrc[c] + k0, base + dst_[c]);
            gl16(lsrc[c] + k0, base + 8192 + dst_[c]);
        }
    };

    f32x4 acc[4][4];
    #pragma unroll
    for (int mi = 0; mi < 4; mi++)
        #pragma unroll
        for (int ni = 0; ni < 4; ni++) acc[mi][ni] = (f32x4){0.f,0.f,0.f,0.f};

    STAGE(0, 0);
    int cur = 0;
    for (int k = 0; k < 16; k++) {
        if (k + 1 < 16) { STAGE(cur ^ 1, (k + 1) << 5); wait_vm<8>(); }
        else wait_vm<0>();
        bar(); sbar0();
        short* Mh = smem + (cur << 14);
        short* Ml = Mh + 8192;
        s16x8 bh[4], bl[4];
        #pragma unroll
        for (int ni = 0; ni < 4; ni++) {
            int br = (wn << 6) + (ni << 4) + llo;
            int bo = (br << 6) + (((lhi | 4) ^ (br & 7)) << 3);
            bh[ni] = *(const s16x8*)&Mh[bo];
            bl[ni] = *(const s16x8*)&Ml[bo];
        }
        #pragma unroll
        for (int mi = 0; mi < 4; mi++) {
            int ar = (wm << 6) + (mi << 4) + llo;
            int ao = (ar << 6) + ((lhi ^ (ar & 7)) << 3);
            s16x8 ah = *(const s16x8*)&Mh[ao];
            s16x8 al = *(const s16x8*)&Ml[ao];
            #pragma unroll
            for (int ni = 0; ni < 4; ni++) {
                acc[mi][ni] = __builtin_amdgcn_mfma_f32_16x16x32_bf16(ah, bh[ni], acc[mi][ni], 0, 0, 0);
                acc[mi][ni] = __builtin_amdgcn_mfma_f32_16x16x32_bf16(ah, bl[ni], acc[mi][ni], 0, 0, 0);
                acc[mi][ni] = __builtin_amdgcn_mfma_f32_16x16x32_bf16(al, bh[ni], acc[mi][ni], 0, 0, 0);
            }
        }
        wait_lgkm0(); sbar0(); bar();
        cur ^= 1;
    }
    __syncthreads();

    short* Pl = smem;
    #pragma unroll
    for (int mi = 0; mi < 4; mi++) {
        int tl = (wm << 4) + (mi << 2) + lhi;
        int tg = t0 + tl;
        float wsum = 0.f; unsigned ab = 0u;
        #pragma unroll
        for (int ni = 0; ni < 4; ni++) {
            int sl = (wn << 6) + (ni << 4) + llo;
            int sg = s0 + sl;
            f32x4 v = acc[mi][ni];
            float wu = 0.f; unsigned bits = 0u;
            if (sg <= tg) {
                float a0 = v[0]*RSC_, a1 = v[1]*RSC_, a2 = v[2]*RSC_, a3 = v[3]*RSC_;
                float m = fmaxf(fmaxf(a0, a1), fmaxf(a2, a3));
                bits = (a0 == m ? 1u : 0u) | (a1 == m ? 2u : 0u)
                     | (a2 == m ? 4u : 0u) | (a3 == m ? 8u : 0u);
                wu = fmaxf(m, 0.f) + log1pf(expf(-fabsf(m)));
                wsum += wu; ab |= bits;
            }
            unsigned short wub = f2bf(wu);
            Pl[(0*32 + tl)*136 + sl] = (bits & 1u) ? (short)wub : (short)0;
            Pl[(1*32 + tl)*136 + sl] = (bits & 2u) ? (short)wub : (short)0;
            Pl[(2*32 + tl)*136 + sl] = (bits & 4u) ? (short)wub : (short)0;
            Pl[(3*32 + tl)*136 + sl] = (bits & 8u) ? (short)wub : (short)0;
        }
        #pragma unroll
        for (int mask = 1; mask <= 8; mask <<= 1) wsum += __shfl_xor(wsum, mask, 64);
        int ai = (int)ab;
        #pragma unroll
        for (int mask = 1; mask <= 8; mask <<= 1) ai |= __shfl_xor(ai, mask, 64);
        if (llo == 0) {
            size_t pidx = ((((size_t)(b*64 + tt) * 16 + st) * 2 + wn) * 32) + tl;
            partS[pidx] = wsum;
            partA[pidx] = (unsigned)ai;
        }
    }
    __syncthreads();
    for (int i = tid; i < 2048; i += 256) {
        int row = i >> 4, g8 = i & 15;
        int n = row >> 5, tl = row & 31;
        u16x8 v = *(const u16x8*)&Pl[row*136 + (g8 << 3)];
        *(u16x8*)(P + ((size_t)((b*4 + n)*T_ + t0 + tl)) * T_ + s0 + (g8 << 3)) = v;
    }
}

// ---------------- PV pass: counted pipeline, bf16 partials, 8-phase k-split -----------
// grid (b:2, tt:16, cc:4, ph:8) = 1024 blocks -> 4 blocks/CU resident.
__global__ __launch_bounds__(256, 4) void pv_k(
    const unsigned short* __restrict__ P, const unsigned short* __restrict__ Vt,
    unsigned short* __restrict__ py)
{
    __shared__ __align__(16) short smem[32768];
    int tid = threadIdx.x;
    int w = tid >> 6, l = tid & 63;
    int wm = w >> 1, wn = w & 1;
    int llo = l & 15, lhi = l >> 4;
    int rl = l >> 3, gs8 = l & 7;
    int rb = w << 5;
    int bid = blockIdx.x;
    int ph = bid & 7, cc = (bid >> 3) & 3, tt = 15 - ((bid >> 5) & 15), b = bid >> 9;
    int t0 = tt << 7, c0 = cc << 7;
    int b4 = b * 4;
    size_t bV = (size_t)b * (NB_*C_);

    size_t pa_[4], pb_[4];
    int dsb_[4];
    #pragma unroll
    for (int i8 = 0; i8 < 4; i8++) {
        int r = rb + (i8 << 3) + rl;
        int sg = (gs8 ^ (r & 7)) << 3;
        pa_[i8] = (size_t)(t0 + r) * T_ + sg;
        pb_[i8] = (size_t)(c0 + r) * T_ + sg;
        dsb_[i8] = (rb + (i8 << 3)) << 6;
    }
    auto STAGE = [&](int cur, int n, int k0) {
        short* base = smem + (cur << 14);
        size_t na = (size_t)(b4 + n) * T_ * T_;
        size_t nb = (bV + (size_t)(n << 9)) * T_;
        #pragma unroll
        for (int i8 = 0; i8 < 4; i8++) {
            gl16(P  + na + pa_[i8] + k0, base + dsb_[i8]);
            gl16(Vt + nb + pb_[i8] + k0, base + 8192 + dsb_[i8]);
        }
    };

    f32x4 acc[4][4];
    #pragma unroll
    for (int mi = 0; mi < 4; mi++)
        #pragma unroll
        for (int ni = 0; ni < 4; ni++) acc[mi][ni] = (f32x4){0.f,0.f,0.f,0.f};

    int first_sb = ph << 7;
    int num_sb = (first_sb <= t0 + 127) ? (((t0 + 127 - first_sb) >> 10) + 1) : 0;
    int nsteps = num_sb << 3;   // 4 n * num_sb * 2 halves

    if (nsteps > 0) {
        int n_p = 0, sb_p = first_sb, h_p = 0;
        auto ADV = [&]() {
            h_p ^= 1;
            if (!h_p) { sb_p += 1024; if (sb_p > t0 + 127) { sb_p = first_sb; n_p++; } }
        };
        STAGE(0, n_p, sb_p + (h_p << 6)); ADV();
        int cur = 0;
        for (int s = 0; s < nsteps; s++) {
            if (s + 1 < nsteps) { STAGE(cur ^ 1, n_p, sb_p + (h_p << 6)); ADV(); wait_vm<8>(); }
            else wait_vm<0>();
            bar(); sbar0();
            short* Ah = smem + (cur << 14);
            short* Bh = Ah + 8192;
            #pragma unroll
            for (int ks = 0; ks < 2; ks++) {
                s16x8 bh[4];
                #pragma unroll
                for (int ni = 0; ni < 4; ni++) {
                    int br = (wn << 6) + (ni << 4) + llo;
                    bh[ni] = *(const s16x8*)&Bh[br*64 + ((((ks << 2) + lhi) ^ (br & 7)) << 3)];
                }
                #pragma unroll
                for (int mi = 0; mi < 4; mi++) {
                    int ar = (wm << 6) + (mi << 4) + llo;
                    s16x8 ah = *(const s16x8*)&Ah[ar*64 + ((((ks << 2) + lhi) ^ (ar & 7)) << 3)];
                    #pragma unroll
                    for (int ni = 0; ni < 4; ni++)
                        acc[mi][ni] = __builtin_amdgcn_mfma_f32_16x16x32_bf16(ah, bh[ni], acc[mi][ni], 0, 0, 0);
                }
            }
            wait_lgkm0(); sbar0(); bar();
            cur ^= 1;
        }
    }
    unsigned short* out = py + (size_t)ph * (BT_*(size_t)C_);
    #pragma unroll
    for (int mi = 0; mi < 4; mi++) {
        int row0 = t0 + (wm << 6) + (mi << 4) + (lhi << 2);
        #pragma unroll
        for (int ni = 0; ni < 4; ni++) {
            int col = c0 + (wn << 6) + (ni << 4) + llo;
            f32x4 v = acc[mi][ni];
            #pragma unroll
            for (int r = 0; r < 4; r++)
                out[(size_t)(b*T_ + row0 + r) * C_ + col] = f2bf(v[r]);
        }
    }
}

// ---------------- combine: 8 bf16 y partials + S/act + sinks -> ybf16 ----------------
__global__ __launch_bounds__(256) void combine3_k(
    const unsigned short* __restrict__ py, const float* __restrict__ partS,
    const unsigned* __restrict__ partA,
    const float* __restrict__ basis, const float* __restrict__ resid_sink,
    unsigned short* __restrict__ ybf)
{
    int bt = blockIdx.x;
    int t = bt & (T_ - 1);
    int b = bt >> 11;
    int i = threadIdx.x;
    int tt32 = t >> 5, tl = t & 31;
    int stmax = tt32 >> 2;
    float S = 0.f; unsigned act = 0u;
    for (int st = 0; st <= stmax; st++) {
        #pragma unroll
        for (int wn = 0; wn < 2; wn++) {
            size_t idx = ((((size_t)(b*64 + tt32) * 16 + st) * 2 + wn) * 32) + tl;
            S += partS[idx];
            act |= partA[idx];
        }
    }
    float y0 = 0.f, y1 = 0.f;
    #pragma unroll
    for (int ph = 0; ph < 8; ph++) {
        y0 += bf2f(py[(size_t)ph * (BT_*(size_t)C_) + (size_t)bt * C_ + i]);
        y1 += bf2f(py[(size_t)ph * (BT_*(size_t)C_) + (size_t)bt * C_ + i + 256]);
    }
    float scale = fminf(1.0f / (S + 1e-6f), 1.0f);
    float residual = 1.0f - scale * S;
    if (t < T_ - 1) act = 0xFu;
    float o0 = scale * y0, o1 = scale * y1;
    #pragma unroll
    for (int n = 0; n < 4; n++) if ((act >> n) & 1u) {
        o0 += basis[n*C_ + i];
        o1 += basis[n*C_ + i + 256];
    }
    o0 += residual * resid_sink[i];
    o1 += residual * resid_sink[i + 256];
    ybf[(size_t)bt * C_ + i]       = f2bf(o0);
    ybf[(size_t)bt * C_ + i + 256] = f2bf(o1);
}

extern "C" void kernel_launch(void* const* d_in, const int* in_sizes, int n_in,
                              void* d_out, int out_size, void* d_ws, size_t ws_size,
                              hipStream_t stream) {
    const float* a    = (const float*)d_in[0];
    const float* x    = (const float*)d_in[1];
    const float* Wq   = (const float*)d_in[2];
    const float* Wk   = (const float*)d_in[3];
    const float* Wv   = (const float*)d_in[4];
    const float* Wo   = (const float*)d_in[5];
    const float* vres = (const float*)d_in[6];
    const float* vbas = (const float*)d_in[7];

    float* ws = (float*)d_ws;
    float* cosT = ws;                              // 524288 f
    float* sinT = cosT + 524288;                   // 524288 f
    float* Qf   = sinT + 524288;                   // 8388608 f (reused as py bf16 x8)
    float* Kf   = Qf + 8388608;                    // 2097152 f (reused: partS/partA/ybf)
    unsigned short* ahi  = (unsigned short*)(Kf + 2097152);
    unsigned short* alo  = ahi  + 2097152;
    unsigned short* xhi  = alo  + 2097152;
    unsigned short* xlo  = xhi  + 2097152;
    unsigned short* Wqth = xlo  + 2097152;
    unsigned short* Wqtl = Wqth + 1048576;
    unsigned short* Wkth = Wqtl + 1048576;
    unsigned short* Wktl = Wkth + 262144;
    unsigned short* Wvth = Wktl + 262144;
    unsigned short* Woth = Wvth + 1048576;
    unsigned short* Qhi  = Woth + 262144;
    unsigned short* Qlo  = Qhi  + 8388608;
    unsigned short* Khi  = Qlo  + 8388608;
    unsigned short* Klo  = Khi  + 2097152;
    unsigned short* Vt   = Klo  + 2097152;
    unsigned short* P    = Vt   + 8388608;         // 33554432 shorts

    unsigned short* py = (unsigned short*)Qf;      // Qf dead after qk_post; 8x4MB fits 32MB
    float* partS = Kf;
    unsigned* partA = (unsigned*)(Kf + 131072);
    unsigned short* ybf = (unsigned short*)(Kf + 262144);

    prep_k<<<6784, 256, 0, stream>>>(a, x, Wq, Wk, Wv, Wo, cosT, sinT,
                                     ahi, alo, xhi, xlo,
                                     Wqth, Wqtl, Wkth, Wktl, Wvth, Woth);

    mm_k<1><<<512, 256, 0, stream>>>(ahi, alo, Wqth, Wqtl, Qf, BT_, 2048, 512);
    mm_k<1><<<128, 256, 0, stream>>>(xhi, xlo, Wkth, Wktl, Kf, BT_, 512, 512);
    mm_v_k<<<512, 256, 0, stream>>>(ahi, Wvth, Vt, BT_, 2048, 512);

    qk_post_k<<<6144, 256, 0, stream>>>(Qf, Kf, cosT, sinT, Qhi, Qlo, Khi, Klo);

    qk_routing_k<<<1088, 256, 0, stream>>>(Qhi, Qlo, Khi, Klo, P, partS, partA);
    pv_k<<<1024, 256, 0, stream>>>(P, Vt, py);
    combine3_k<<<BT_, 256, 0, stream>>>(py, partS, partA, vbas, vres, ybf);

    mm_k<0><<<128, 256, 0, stream>>>(ybf, nullptr, Woth, nullptr, (float*)d_out, BT_, 512, 512);
}

// Round 15
// 217.546 us; speedup vs baseline: 1.0170x; 1.0015x over previous
//
#include <hip/hip_runtime.h>
#include <math.h>

#define B_    2
#define T_    2048
#define C_    512
#define NB_   4
#define HALF_ 256
#define BT_   (B_*T_)
#define EPS_  1.1920929e-07f
#define RSC_  0.044194173824159216f   // 1/sqrt(512)

using f32x4 = __attribute__((ext_vector_type(4))) float;
using s16x8 = __attribute__((ext_vector_type(8))) short;
using u16x8 = __attribute__((ext_vector_type(8))) unsigned short;

__device__ __forceinline__ unsigned short f2bf(float f) {
    unsigned x = __float_as_uint(f);
    unsigned r = (x + 0x7fffu + ((x >> 16) & 1u)) >> 16;
    return (unsigned short)r;
}
__device__ __forceinline__ float bf2f(unsigned short h) {
    return __uint_as_float(((unsigned)h) << 16);
}

// direct global->LDS 16B: per-lane global src, wave-uniform LDS base (+lane*16B in HW)
__device__ __forceinline__ void gl16(const void* g, void* l) {
    __builtin_amdgcn_global_load_lds(
        (const __attribute__((address_space(1))) unsigned int*)g,
        (__attribute__((address_space(3))) unsigned int*)l, 16, 0, 0);
}

template<int N> __device__ __forceinline__ void wait_vm() {
    if constexpr (N == 0)      asm volatile("s_waitcnt vmcnt(0)" ::: "memory");
    else if constexpr (N == 4) asm volatile("s_waitcnt vmcnt(4)" ::: "memory");
    else                       asm volatile("s_waitcnt vmcnt(8)" ::: "memory");
}
__device__ __forceinline__ void wait_lgkm0() {
    asm volatile("s_waitcnt lgkmcnt(0)" ::: "memory");
}
__device__ __forceinline__ void bar() { __builtin_amdgcn_s_barrier(); }
__device__ __forceinline__ void sbar0() { __builtin_amdgcn_sched_barrier(0); }

// ---------------- fused prep: rope tables + a/x hi-lo cast + 4 weight transpose-casts --
__global__ __launch_bounds__(256) void prep_k(
    const float* __restrict__ a, const float* __restrict__ x,
    const float* __restrict__ Wq, const float* __restrict__ Wk,
    const float* __restrict__ Wv, const float* __restrict__ Wo,
    float* __restrict__ cosT, float* __restrict__ sinT,
    unsigned short* __restrict__ ahi, unsigned short* __restrict__ alo,
    unsigned short* __restrict__ xhi, unsigned short* __restrict__ xlo,
    unsigned short* __restrict__ Wqth, unsigned short* __restrict__ Wqtl,
    unsigned short* __restrict__ Wkth, unsigned short* __restrict__ Wktl,
    unsigned short* __restrict__ Wvth, unsigned short* __restrict__ Woth)
{
    __shared__ float tile[64][65];
    int bid = blockIdx.x;
    int tid = threadIdx.x;
    if (bid < 2048) {
        int t = bid;
        float ex   = (float)tid / (float)HALF_;
        float invf = 1.0f / powf(10000.0f, ex);
        float ang  = (float)t * invf;
        float sv, cv;
        sincosf(ang, &sv, &cv);
        cosT[t*HALF_ + tid] = cv;
        sinT[t*HALF_ + tid] = sv;
        return;
    }
    if (bid < 6144) {
        int i = (bid - 2048) * 256 + tid;
        const float* src; unsigned short *hi, *lo;
        if (i < 524288) { src = a; hi = ahi; lo = alo; }
        else { i -= 524288; src = x; hi = xhi; lo = xlo; }
        float4 v = ((const float4*)src)[i];
        ushort4 h, l;
        h.x = f2bf(v.x); l.x = f2bf(v.x - bf2f(h.x));
        h.y = f2bf(v.y); l.y = f2bf(v.y - bf2f(h.y));
        h.z = f2bf(v.z); l.z = f2bf(v.z - bf2f(h.z));
        h.w = f2bf(v.w); l.w = f2bf(v.w - bf2f(h.w));
        ((ushort4*)hi)[i] = h;
        ((ushort4*)lo)[i] = l;
        return;
    }
    const float* W; unsigned short *Whi, *Wlo; int N, blk; int wantLo;
    if (bid < 6400)      { W = Wq; Whi = Wqth; Wlo = Wqtl; N = 2048; blk = bid - 6144; wantLo = 1; }
    else if (bid < 6464) { W = Wk; Whi = Wkth; Wlo = Wktl; N = 512;  blk = bid - 6400; wantLo = 1; }
    else if (bid < 6720) { W = Wv; Whi = Wvth; Wlo = nullptr; N = 2048; blk = bid - 6464; wantLo = 0; }
    else                 { W = Wo; Whi = Woth; Wlo = nullptr; N = 512;  blk = bid - 6720; wantLo = 0; }
    int K = 512;
    int nbt = N >> 6;
    int nb = blk % nbt, kb = blk / nbt;
    int ty = tid >> 6, tx = tid & 63;
    for (int i = ty; i < 64; i += 4)
        tile[i][tx] = W[(size_t)(kb*64 + i) * N + nb*64 + tx];
    __syncthreads();
    for (int j = ty; j < 64; j += 4) {
        float v = tile[tx][j];
        unsigned short h = f2bf(v);
        size_t o = (size_t)(nb*64 + j) * K + kb*64 + tx;
        Whi[o] = h;
        if (wantLo) Wlo[o] = f2bf(v - bf2f(h));
    }
}

// ---------------- generic MFMA GEMM: C[M][N] fp32 = A[M][K] @ Bt[N][K] ----------------
// 128x128 tile, BK=32, counted-vmcnt 2-deep pipeline.
// LDS: interleaved [A|B] rows of 128B (64 shorts), slot = g ^ (row&7).
template<int SPLIT>
__global__ __launch_bounds__(256, SPLIT ? 2 : 4) void mm_k(
    const unsigned short* __restrict__ Ahi, const unsigned short* __restrict__ Alo,
    const unsigned short* __restrict__ Bhi, const unsigned short* __restrict__ Blo,
    float* __restrict__ C, int M, int N, int K)
{
    constexpr int BUFS = SPLIT ? 16384 : 8192;   // shorts per buffer
    __shared__ __align__(16) short smem[2 * BUFS];

    int tid = threadIdx.x;
    int w = tid >> 6, l = tid & 63;
    int wm = w >> 1, wn = w & 1;
    int llo = l & 15, lhi = l >> 4;
    int rl8 = l >> 3, sl8 = l & 7;
    int nwg = gridDim.x;
    int bid = blockIdx.x;
    int sb = (bid & 7) * (nwg >> 3) + (bid >> 3);   // XCD-chunked (nwg%8==0)
    int nbt = N >> 7;
    int bx = sb % nbt, by = sb / nbt;
    int m0 = by << 7, n0 = bx << 7;

    const unsigned short* hs[4];
    const unsigned short* ls[4];
    int dst_[4];
    #pragma unroll
    for (int c = 0; c < 4; c++) {
        int r = (w << 5) + (c << 3) + rl8;
        int sp = sl8 ^ (r & 7);
        size_t off = (sp < 4) ? ((size_t)(m0 + r) * K + (sp << 3))
                              : ((size_t)(n0 + r) * K + ((sp - 4) << 3));
        hs[c] = (sp < 4 ? Ahi : Bhi) + off;
        if constexpr (SPLIT) ls[c] = (sp < 4 ? Alo : Blo) + off;
        dst_[c] = (w << 11) + (c << 9);   // shorts
    }
    auto STAGE = [&](int cur, int k0) {
        short* base = smem + cur * BUFS;
        #pragma unroll
        for (int c = 0; c < 4; c++) {
            gl16(hs[c] + k0, base + dst_[c]);
            if constexpr (SPLIT) gl16(ls[c] + k0, base + 8192 + dst_[c]);
        }
    };

    f32x4 acc[4][4];
    #pragma unroll
    for (int mi = 0; mi < 4; mi++)
        #pragma unroll
        for (int ni = 0; ni < 4; ni++) acc[mi][ni] = (f32x4){0.f,0.f,0.f,0.f};

    const int NK = K >> 5;
    STAGE(0, 0);
    int cur = 0;
    for (int k = 0; k < NK; k++) {
        if (k + 1 < NK) { STAGE(cur ^ 1, (k + 1) << 5); wait_vm<SPLIT ? 8 : 4>(); }
        else wait_vm<0>();
        bar(); sbar0();
        short* Mh = smem + cur * BUFS;
        short* Ml = Mh + 8192;
        s16x8 bh[4], bl[4];
        #pragma unroll
        for (int ni = 0; ni < 4; ni++) {
            int br = (wn << 6) + (ni << 4) + llo;
            int bo = (br << 6) + (((lhi | 4) ^ (br & 7)) << 3);
            bh[ni] = *(const s16x8*)&Mh[bo];
            if constexpr (SPLIT) bl[ni] = *(const s16x8*)&Ml[bo];
        }
        if constexpr (!SPLIT) __builtin_amdgcn_s_setprio(1);
        #pragma unroll
        for (int mi = 0; mi < 4; mi++) {
            int ar = (wm << 6) + (mi << 4) + llo;
            int ao = (ar << 6) + ((lhi ^ (ar & 7)) << 3);
            s16x8 ah = *(const s16x8*)&Mh[ao];
            s16x8 al;
            if constexpr (SPLIT) al = *(const s16x8*)&Ml[ao];
            #pragma unroll
            for (int ni = 0; ni < 4; ni++) {
                acc[mi][ni] = __builtin_amdgcn_mfma_f32_16x16x32_bf16(ah, bh[ni], acc[mi][ni], 0, 0, 0);
                if constexpr (SPLIT) {
                    acc[mi][ni] = __builtin_amdgcn_mfma_f32_16x16x32_bf16(ah, bl[ni], acc[mi][ni], 0, 0, 0);
                    acc[mi][ni] = __builtin_amdgcn_mfma_f32_16x16x32_bf16(al, bh[ni], acc[mi][ni], 0, 0, 0);
                }
            }
        }
        if constexpr (!SPLIT) __builtin_amdgcn_s_setprio(0);
        wait_lgkm0(); sbar0(); bar();
        cur ^= 1;
    }
    #pragma unroll
    for (int mi = 0; mi < 4; mi++) {
        int row0 = m0 + (wm << 6) + (mi << 4) + (lhi << 2);
        #pragma unroll
        for (int ni = 0; ni < 4; ni++) {
            int col = n0 + (wn << 6) + (ni << 4) + llo;
            f32x4 v = acc[mi][ni];
            #pragma unroll
            for (int r = 0; r < 4; r++)
                C[(size_t)(row0 + r) * N + col] = v[r];
        }
    }
}

// ---------------- V GEMM (plain bf16), interleaved rows, transposed-bf16 epilogue -----
__global__ __launch_bounds__(256, 4) void mm_v_k(
    const unsigned short* __restrict__ Ahi,
    const unsigned short* __restrict__ Bhi,
    unsigned short* __restrict__ Vt, int M, int N, int K)
{
    __shared__ __align__(16) short smem[2 * 8192];
    int tid = threadIdx.x;
    int w = tid >> 6, l = tid & 63;
    int wm = w >> 1, wn = w & 1;
    int llo = l & 15, lhi = l >> 4;
    int rl8 = l >> 3, sl8 = l & 7;
    int nwg = gridDim.x;
    int bid = blockIdx.x;
    int sb = (bid & 7) * (nwg >> 3) + (bid >> 3);
    int nbt = N >> 7;
    int bx = sb % nbt, by = sb / nbt;
    int m0 = by << 7, n0 = bx << 7;

    const unsigned short* hs[4];
    int dst_[4];
    #pragma unroll
    for (int c = 0; c < 4; c++) {
        int r = (w << 5) + (c << 3) + rl8;
        int sp = sl8 ^ (r & 7);
        size_t off = (sp < 4) ? ((size_t)(m0 + r) * K + (sp << 3))
                              : ((size_t)(n0 + r) * K + ((sp - 4) << 3));
        hs[c] = (sp < 4 ? Ahi : Bhi) + off;
        dst_[c] = (w << 11) + (c << 9);
    }
    auto STAGE = [&](int cur, int k0) {
        short* base = smem + cur * 8192;
        #pragma unroll
        for (int c = 0; c < 4; c++) gl16(hs[c] + k0, base + dst_[c]);
    };

    f32x4 acc[4][4];
    #pragma unroll
    for (int mi = 0; mi < 4; mi++)
        #pragma unroll
        for (int ni = 0; ni < 4; ni++) acc[mi][ni] = (f32x4){0.f,0.f,0.f,0.f};

    const int NK = K >> 5;
    STAGE(0, 0);
    int cur = 0;
    for (int k = 0; k < NK; k++) {
        if (k + 1 < NK) { STAGE(cur ^ 1, (k + 1) << 5); wait_vm<4>(); }
        else wait_vm<0>();
        bar(); sbar0();
        short* Mh = smem + cur * 8192;
        s16x8 bh[4];
        #pragma unroll
        for (int ni = 0; ni < 4; ni++) {
            int br = (wn << 6) + (ni << 4) + llo;
            bh[ni] = *(const s16x8*)&Mh[(br << 6) + (((lhi | 4) ^ (br & 7)) << 3)];
        }
        __builtin_amdgcn_s_setprio(1);
        #pragma unroll
        for (int mi = 0; mi < 4; mi++) {
            int ar = (wm << 6) + (mi << 4) + llo;
            s16x8 ah = *(const s16x8*)&Mh[(ar << 6) + ((lhi ^ (ar & 7)) << 3)];
            #pragma unroll
            for (int ni = 0; ni < 4; ni++)
                acc[mi][ni] = __builtin_amdgcn_mfma_f32_16x16x32_bf16(ah, bh[ni], acc[mi][ni], 0, 0, 0);
        }
        __builtin_amdgcn_s_setprio(0);
        wait_lgkm0(); sbar0(); bar();
        cur ^= 1;
    }
    #pragma unroll
    for (int mi = 0; mi < 4; mi++) {
        int row0 = m0 + (wm << 6) + (mi << 4) + (lhi << 2);
        int b = row0 >> 11, t = row0 & (T_ - 1);
        #pragma unroll
        for (int ni = 0; ni < 4; ni++) {
            int col = n0 + (wn << 6) + (ni << 4) + llo;
            f32x4 v = acc[mi][ni];
            ushort4 o;
            o.x = f2bf(v[0]); o.y = f2bf(v[1]); o.z = f2bf(v[2]); o.w = f2bf(v[3]);
            *(ushort4*)(Vt + ((size_t)(b*(NB_*C_) + col)) * T_ + t) = o;
        }
    }
}

// ---------------- fused Q RMSNorm+RoPE and K RoPE -> hi/lo bf16 ----------------
__global__ __launch_bounds__(256) void qk_post_k(
    const float* __restrict__ Qf, const float* __restrict__ Kf,
    const float* __restrict__ cosT, const float* __restrict__ sinT,
    unsigned short* __restrict__ Qhi, unsigned short* __restrict__ Qlo,
    unsigned short* __restrict__ Khi, unsigned short* __restrict__ Klo)
{
    int bid = blockIdx.x;
    if (bid < 4096) {
        int bt = bid;
        int t  = bt & (T_ - 1);
        int w = threadIdx.x >> 6, l = threadIdx.x & 63;
        const float* row = Qf + (size_t)bt * (NB_*C_) + (w << 9);
        int i0 = l << 2;
        float4 x1 = *(const float4*)(row + i0);
        float4 x2 = *(const float4*)(row + i0 + HALF_);
        float s = x1.x*x1.x + x1.y*x1.y + x1.z*x1.z + x1.w*x1.w
                + x2.x*x2.x + x2.y*x2.y + x2.z*x2.z + x2.w*x2.w;
        #pragma unroll
        for (int mask = 1; mask <= 32; mask <<= 1) s += __shfl_xor(s, mask, 64);
        float r = rsqrtf(s * (1.0f / (float)C_) + EPS_);
        float4 cv = *(const float4*)(cosT + t*HALF_ + i0);
        float4 sv = *(const float4*)(sinT + t*HALF_ + i0);
        float v1[4], v2[4];
        v1[0] = x1.x*r*cv.x - x2.x*r*sv.x;  v2[0] = x2.x*r*cv.x + x1.x*r*sv.x;
        v1[1] = x1.y*r*cv.y - x2.y*r*sv.y;  v2[1] = x2.y*r*cv.y + x1.y*r*sv.y;
        v1[2] = x1.z*r*cv.z - x2.z*r*sv.z;  v2[2] = x2.z*r*cv.z + x1.z*r*sv.z;
        v1[3] = x1.w*r*cv.w - x2.w*r*sv.w;  v2[3] = x2.w*r*cv.w + x1.w*r*sv.w;
        size_t o = (size_t)bt * (NB_*C_) + (w << 9) + i0;
        ushort4 h1, h2, l1, l2;
        h1.x = f2bf(v1[0]); l1.x = f2bf(v1[0] - bf2f(h1.x));
        h1.y = f2bf(v1[1]); l1.y = f2bf(v1[1] - bf2f(h1.y));
        h1.z = f2bf(v1[2]); l1.z = f2bf(v1[2] - bf2f(h1.z));
        h1.w = f2bf(v1[3]); l1.w = f2bf(v1[3] - bf2f(h1.w));
        h2.x = f2bf(v2[0]); l2.x = f2bf(v2[0] - bf2f(h2.x));
        h2.y = f2bf(v2[1]); l2.y = f2bf(v2[1] - bf2f(h2.y));
        h2.z = f2bf(v2[2]); l2.z = f2bf(v2[2] - bf2f(h2.z));
        h2.w = f2bf(v2[3]); l2.w = f2bf(v2[3] - bf2f(h2.w));
        *(ushort4*)(Qhi + o)          = h1;
        *(ushort4*)(Qhi + o + HALF_)  = h2;
        *(ushort4*)(Qlo + o)          = l1;
        *(ushort4*)(Qlo + o + HALF_)  = l2;
        return;
    }
    int sub = threadIdx.x >> 7, l = threadIdx.x & 127;
    int bt = (bid - 4096) * 2 + sub;
    int t  = bt & (T_ - 1);
    const float* row = Kf + (size_t)bt * C_;
    int i0 = l << 1;
    float2 x1 = *(const float2*)(row + i0);
    float2 x2 = *(const float2*)(row + i0 + HALF_);
    float2 cv = *(const float2*)(cosT + t*HALF_ + i0);
    float2 sv = *(const float2*)(sinT + t*HALF_ + i0);
    float v1x = x1.x*cv.x - x2.x*sv.x, v2x = x2.x*cv.x + x1.x*sv.x;
    float v1y = x1.y*cv.y - x2.y*sv.y, v2y = x2.y*cv.y + x1.y*sv.y;
    size_t o = (size_t)bt * C_ + i0;
    ushort2 h1, h2, l1, l2;
    h1.x = f2bf(v1x); l1.x = f2bf(v1x - bf2f(h1.x));
    h1.y = f2bf(v1y); l1.y = f2bf(v1y - bf2f(h1.y));
    h2.x = f2bf(v2x); l2.x = f2bf(v2x - bf2f(h2.x));
    h2.y = f2bf(v2y); l2.y = f2bf(v2y - bf2f(h2.y));
    *(ushort2*)(Khi + o)         = h1;
    *(ushort2*)(Khi + o + HALF_) = h2;
    *(ushort2*)(Klo + o)         = l1;
    *(ushort2*)(Klo + o + HALF_) = l2;
}

// ---------------- QK + routing pass: persistent tail-balanced grid (1024 -> 1088 tiles)
__global__ __launch_bounds__(256, 2) void qk_routing_k(
    const unsigned short* __restrict__ Qhi, const unsigned short* __restrict__ Qlo,
    const unsigned short* __restrict__ Khi, const unsigned short* __restrict__ Klo,
    unsigned short* __restrict__ P, float* __restrict__ partS, unsigned* __restrict__ partA)
{
    __shared__ __align__(16) short smem[32768];

    int tid = threadIdx.x;
    int w = tid >> 6, l = tid & 63;
    int wm = w >> 1, wn = w & 1;
    int llo = l & 15, lhi = l >> 4;
    int rl8 = l >> 3, sl8 = l & 7;
    int bid = blockIdx.x;

    for (int j0 = bid; j0 < 1088; j0 += 1024) {
        int j = (j0 & 7) * 136 + (j0 >> 3);        // bijective XCD-chunked map on [0,1088)
        int b = (j >= 544) ? 1 : 0;
        int j2 = j - 544 * b;
        int q = (int)((sqrtf(1.0f + 2.0f*(float)j2) - 1.0f) * 0.5f);
        if (2*(q+1)*(q+2) <= j2) q++;
        if (2*q*(q+1) > j2) q--;
        int r0 = j2 - 2*q*(q+1);
        int tloc = r0 / (q+1);
        int st = r0 - tloc*(q+1);
        int tt = (q << 2) + tloc;
        int t0 = tt << 5, s0 = st << 7;

        const unsigned short* hsrc[4];
        const unsigned short* lsrc[4];
        int dst_[4];
        #pragma unroll
        for (int c = 0; c < 4; c++) {
            int r = (w << 5) + (c << 3) + rl8;
            int sp = sl8 ^ (r & 7);
            size_t off = (sp < 4)
                ? ((size_t)(b*T_ + t0 + (r >> 2)) * (NB_*C_) + ((r & 3) << 9) + (sp << 3))
                : ((size_t)(b*T_ + s0 + r) * C_ + ((sp - 4) << 3));
            hsrc[c] = (sp < 4 ? Qhi : Khi) + off;
            lsrc[c] = (sp < 4 ? Qlo : Klo) + off;
            dst_[c] = (w << 11) + (c << 9);
        }
        auto STAGE = [&](int cur, int k0) {
            short* base = smem + (cur << 14);
            #pragma unroll
            for (int c = 0; c < 4; c++) {
                gl16(hsrc[c] + k0, base + dst_[c]);
                gl16(lsrc[c] + k0, base + 8192 + dst_[c]);
            }
        };

        f32x4 acc[4][4];
        #pragma unroll
        for (int mi = 0; mi < 4; mi++)
            #pragma unroll
            for (int ni = 0; ni < 4; ni++) acc[mi][ni] = (f32x4){0.f,0.f,0.f,0.f};

        if (j0 != bid) __syncthreads();            // protect smem from previous tile's epilogue
        STAGE(0, 0);
        int cur = 0;
        for (int k = 0; k < 16; k++) {
            if (k + 1 < 16) { STAGE(cur ^ 1, (k + 1) << 5); wait_vm<8>(); }
            else wait_vm<0>();
            bar(); sbar0();
            short* Mh = smem + (cur << 14);
            short* Ml = Mh + 8192;
            s16x8 bh[4], bl[4];
            #pragma unroll
            for (int ni = 0; ni < 4; ni++) {
                int br = (wn << 6) + (ni << 4) + llo;
                int bo = (br << 6) + (((lhi | 4) ^ (br & 7)) << 3);
                bh[ni] = *(const s16x8*)&Mh[bo];
                bl[ni] = *(const s16x8*)&Ml[bo];
            }
            #pragma unroll
            for (int mi = 0; mi < 4; mi++) {
                int ar = (wm << 6) + (mi << 4) + llo;
                int ao = (ar << 6) + ((lhi ^ (ar & 7)) << 3);
                s16x8 ah = *(const s16x8*)&Mh[ao];
                s16x8 al = *(const s16x8*)&Ml[ao];
                #pragma unroll
                for (int ni = 0; ni < 4; ni++) {
                    acc[mi][ni] = __builtin_amdgcn_mfma_f32_16x16x32_bf16(ah, bh[ni], acc[mi][ni], 0, 0, 0);
                    acc[mi][ni] = __builtin_amdgcn_mfma_f32_16x16x32_bf16(ah, bl[ni], acc[mi][ni], 0, 0, 0);
                    acc[mi][ni] = __builtin_amdgcn_mfma_f32_16x16x32_bf16(al, bh[ni], acc[mi][ni], 0, 0, 0);
                }
            }
            wait_lgkm0(); sbar0(); bar();
            cur ^= 1;
        }
        __syncthreads();   // full drain before smem reuse as Pl

        // ---- routing epilogue (lean); P staged in LDS [4][32][136] ----
        short* Pl = smem;
        #pragma unroll
        for (int mi = 0; mi < 4; mi++) {
            int tl = (wm << 4) + (mi << 2) + lhi;
            int tg = t0 + tl;
            float wsum = 0.f; unsigned ab = 0u;
            #pragma unroll
            for (int ni = 0; ni < 4; ni++) {
                int sl = (wn << 6) + (ni << 4) + llo;
                int sg = s0 + sl;
                f32x4 v = acc[mi][ni];
                float wu = 0.f; unsigned bits = 0u;
                if (sg <= tg) {
                    float a0 = v[0]*RSC_, a1 = v[1]*RSC_, a2 = v[2]*RSC_, a3 = v[3]*RSC_;
                    float m = fmaxf(fmaxf(a0, a1), fmaxf(a2, a3));
                    bits = (a0 == m ? 1u : 0u) | (a1 == m ? 2u : 0u)
                         | (a2 == m ? 4u : 0u) | (a3 == m ? 8u : 0u);
                    wu = fmaxf(m, 0.f) + log1pf(expf(-fabsf(m)));
                    wsum += wu; ab |= bits;
                }
                unsigned short wub = f2bf(wu);
                Pl[(0*32 + tl)*136 + sl] = (bits & 1u) ? (short)wub : (short)0;
                Pl[(1*32 + tl)*136 + sl] = (bits & 2u) ? (short)wub : (short)0;
                Pl[(2*32 + tl)*136 + sl] = (bits & 4u) ? (short)wub : (short)0;
                Pl[(3*32 + tl)*136 + sl] = (bits & 8u) ? (short)wub : (short)0;
            }
            #pragma unroll
            for (int mask = 1; mask <= 8; mask <<= 1) wsum += __shfl_xor(wsum, mask, 64);
            int ai = (int)ab;
            #pragma unroll
            for (int mask = 1; mask <= 8; mask <<= 1) ai |= __shfl_xor(ai, mask, 64);
            if (llo == 0) {
                size_t pidx = ((((size_t)(b*64 + tt) * 16 + st) * 2 + wn) * 32) + tl;
                partS[pidx] = wsum;
                partA[pidx] = (unsigned)ai;
            }
        }
        __syncthreads();
        for (int i = tid; i < 2048; i += 256) {
            int row = i >> 4, g8 = i & 15;
            int n = row >> 5, tl = row & 31;
            u16x8 v = *(const u16x8*)&Pl[row*136 + (g8 << 3)];
            *(u16x8*)(P + ((size_t)((b*4 + n)*T_ + t0 + tl)) * T_ + s0 + (g8 << 3)) = v;
        }
    }
}

// ---------------- PV pass: counted pipeline, bf16 partials, 8-phase k-split -----------
// grid (b:2, tt:16, cc:4, ph:8) = 1024 blocks -> 4 blocks/CU resident.
__global__ __launch_bounds__(256, 4) void pv_k(
    const unsigned short* __restrict__ P, const unsigned short* __restrict__ Vt,
    unsigned short* __restrict__ py)
{
    __shared__ __align__(16) short smem[32768];
    int tid = threadIdx.x;
    int w = tid >> 6, l = tid & 63;
    int wm = w >> 1, wn = w & 1;
    int llo = l & 15, lhi = l >> 4;
    int rl = l >> 3, gs8 = l & 7;
    int rb = w << 5;
    int bid = blockIdx.x;
    int ph = bid & 7, cc = (bid >> 3) & 3, tt = 15 - ((bid >> 5) & 15), b = bid >> 9;
    int t0 = tt << 7, c0 = cc << 7;
    int b4 = b * 4;
    size_t bV = (size_t)b * (NB_*C_);

    size_t pa_[4], pb_[4];
    int dsb_[4];
    #pragma unroll
    for (int i8 = 0; i8 < 4; i8++) {
        int r = rb + (i8 << 3) + rl;
        int sg = (gs8 ^ (r & 7)) << 3;
        pa_[i8] = (size_t)(t0 + r) * T_ + sg;
        pb_[i8] = (size_t)(c0 + r) * T_ + sg;
        dsb_[i8] = (rb + (i8 << 3)) << 6;
    }
    auto STAGE = [&](int cur, int n, int k0) {
        short* base = smem + (cur << 14);
        size_t na = (size_t)(b4 + n) * T_ * T_;
        size_t nb = (bV + (size_t)(n << 9)) * T_;
        #pragma unroll
        for (int i8 = 0; i8 < 4; i8++) {
            gl16(P  + na + pa_[i8] + k0, base + dsb_[i8]);
            gl16(Vt + nb + pb_[i8] + k0, base + 8192 + dsb_[i8]);
        }
    };

    f32x4 acc[4][4];
    #pragma unroll
    for (int mi = 0; mi < 4; mi++)
        #pragma unroll
        for (int ni = 0; ni < 4; ni++) acc[mi][ni] = (f32x4){0.f,0.f,0.f,0.f};

    int first_sb = ph << 7;
    int num_sb = (first_sb <= t0 + 127) ? (((t0 + 127 - first_sb) >> 10) + 1) : 0;
    int nsteps = num_sb << 3;   // 4 n * num_sb * 2 halves

    if (nsteps > 0) {
        int n_p = 0, sb_p = first_sb, h_p = 0;
        auto ADV = [&]() {
            h_p ^= 1;
            if (!h_p) { sb_p += 1024; if (sb_p > t0 + 127) { sb_p = first_sb; n_p++; } }
        };
        STAGE(0, n_p, sb_p + (h_p << 6)); ADV();
        int cur = 0;
        for (int s = 0; s < nsteps; s++) {
            if (s + 1 < nsteps) { STAGE(cur ^ 1, n_p, sb_p + (h_p << 6)); ADV(); wait_vm<8>(); }
            else wait_vm<0>();
            bar(); sbar0();
            short* Ah = smem + (cur << 14);
            short* Bh = Ah + 8192;
            __builtin_amdgcn_s_setprio(1);
            #pragma unroll
            for (int ks = 0; ks < 2; ks++) {
                s16x8 bh[4];
                #pragma unroll
                for (int ni = 0; ni < 4; ni++) {
                    int br = (wn << 6) + (ni << 4) + llo;
                    bh[ni] = *(const s16x8*)&Bh[br*64 + ((((ks << 2) + lhi) ^ (br & 7)) << 3)];
                }
                #pragma unroll
                for (int mi = 0; mi < 4; mi++) {
                    int ar = (wm << 6) + (mi << 4) + llo;
                    s16x8 ah = *(const s16x8*)&Ah[ar*64 + ((((ks << 2) + lhi) ^ (ar & 7)) << 3)];
                    #pragma unroll
                    for (int ni = 0; ni < 4; ni++)
                        acc[mi][ni] = __builtin_amdgcn_mfma_f32_16x16x32_bf16(ah, bh[ni], acc[mi][ni], 0, 0, 0);
                }
            }
            __builtin_amdgcn_s_setprio(0);
            wait_lgkm0(); sbar0(); bar();
            cur ^= 1;
        }
    }
    unsigned short* out = py + (size_t)ph * (BT_*(size_t)C_);
    #pragma unroll
    for (int mi = 0; mi < 4; mi++) {
        int row0 = t0 + (wm << 6) + (mi << 4) + (lhi << 2);
        #pragma unroll
        for (int ni = 0; ni < 4; ni++) {
            int col = c0 + (wn << 6) + (ni << 4) + llo;
            f32x4 v = acc[mi][ni];
            #pragma unroll
            for (int r = 0; r < 4; r++)
                out[(size_t)(b*T_ + row0 + r) * C_ + col] = f2bf(v[r]);
        }
    }
}

// ---------------- combine: 8 bf16 y partials + S/act + sinks -> ybf16 ----------------
__global__ __launch_bounds__(256) void combine3_k(
    const unsigned short* __restrict__ py, const float* __restrict__ partS,
    const unsigned* __restrict__ partA,
    const float* __restrict__ basis, const float* __restrict__ resid_sink,
    unsigned short* __restrict__ ybf)
{
    int bt = blockIdx.x;
    int t = bt & (T_ - 1);
    int b = bt >> 11;
    int i = threadIdx.x;
    int tt32 = t >> 5, tl = t & 31;
    int stmax = tt32 >> 2;
    float S = 0.f; unsigned act = 0u;
    for (int st = 0; st <= stmax; st++) {
        #pragma unroll
        for (int wn = 0; wn < 2; wn++) {
            size_t idx = ((((size_t)(b*64 + tt32) * 16 + st) * 2 + wn) * 32) + tl;
            S += partS[idx];
            act |= partA[idx];
        }
    }
    float y0 = 0.f, y1 = 0.f;
    #pragma unroll
    for (int ph = 0; ph < 8; ph++) {
        y0 += bf2f(py[(size_t)ph * (BT_*(size_t)C_) + (size_t)bt * C_ + i]);
        y1 += bf2f(py[(size_t)ph * (BT_*(size_t)C_) + (size_t)bt * C_ + i + 256]);
    }
    float scale = fminf(1.0f / (S + 1e-6f), 1.0f);
    float residual = 1.0f - scale * S;
    if (t < T_ - 1) act = 0xFu;
    float o0 = scale * y0, o1 = scale * y1;
    #pragma unroll
    for (int n = 0; n < 4; n++) if ((act >> n) & 1u) {
        o0 += basis[n*C_ + i];
        o1 += basis[n*C_ + i + 256];
    }
    o0 += residual * resid_sink[i];
    o1 += residual * resid_sink[i + 256];
    ybf[(size_t)bt * C_ + i]       = f2bf(o0);
    ybf[(size_t)bt * C_ + i + 256] = f2bf(o1);
}

extern "C" void kernel_launch(void* const* d_in, const int* in_sizes, int n_in,
                              void* d_out, int out_size, void* d_ws, size_t ws_size,
                              hipStream_t stream) {
    const float* a    = (const float*)d_in[0];
    const float* x    = (const float*)d_in[1];
    const float* Wq   = (const float*)d_in[2];
    const float* Wk   = (const float*)d_in[3];
    const float* Wv   = (const float*)d_in[4];
    const float* Wo   = (const float*)d_in[5];
    const float* vres = (const float*)d_in[6];
    const float* vbas = (const float*)d_in[7];

    float* ws = (float*)d_ws;
    float* cosT = ws;                              // 524288 f
    float* sinT = cosT + 524288;                   // 524288 f
    float* Qf   = sinT + 524288;                   // 8388608 f (reused as py bf16 x8)
    float* Kf   = Qf + 8388608;                    // 2097152 f (reused: partS/partA/ybf)
    unsigned short* ahi  = (unsigned short*)(Kf + 2097152);
    unsigned short* alo  = ahi  + 2097152;
    unsigned short* xhi  = alo  + 2097152;
    unsigned short* xlo  = xhi  + 2097152;
    unsigned short* Wqth = xlo  + 2097152;
    unsigned short* Wqtl = Wqth + 1048576;
    unsigned short* Wkth = Wqtl + 1048576;
    unsigned short* Wktl = Wkth + 262144;
    unsigned short* Wvth = Wktl + 262144;
    unsigned short* Woth = Wvth + 1048576;
    unsigned short* Qhi  = Woth + 262144;
    unsigned short* Qlo  = Qhi  + 8388608;
    unsigned short* Khi  = Qlo  + 8388608;
    unsigned short* Klo  = Khi  + 2097152;
    unsigned short* Vt   = Klo  + 2097152;
    unsigned short* P    = Vt   + 8388608;         // 33554432 shorts

    unsigned short* py = (unsigned short*)Qf;      // Qf dead after qk_post; 8x4MB fits 32MB
    float* partS = Kf;
    unsigned* partA = (unsigned*)(Kf + 131072);
    unsigned short* ybf = (unsigned short*)(Kf + 262144);

    prep_k<<<6784, 256, 0, stream>>>(a, x, Wq, Wk, Wv, Wo, cosT, sinT,
                                     ahi, alo, xhi, xlo,
                                     Wqth, Wqtl, Wkth, Wktl, Wvth, Woth);

    mm_k<1><<<512, 256, 0, stream>>>(ahi, alo, Wqth, Wqtl, Qf, BT_, 2048, 512);
    mm_k<1><<<128, 256, 0, stream>>>(xhi, xlo, Wkth, Wktl, Kf, BT_, 512, 512);
    mm_v_k<<<512, 256, 0, stream>>>(ahi, Wvth, Vt, BT_, 2048, 512);

    qk_post_k<<<6144, 256, 0, stream>>>(Qf, Kf, cosT, sinT, Qhi, Qlo, Khi, Klo);

    qk_routing_k<<<1024, 256, 0, stream>>>(Qhi, Qlo, Khi, Klo, P, partS, partA);
    pv_k<<<1024, 256, 0, stream>>>(P, Vt, py);
    combine3_k<<<BT_, 256, 0, stream>>>(py, partS, partA, vbas, vres, ybf);

    mm_k<0><<<128, 256, 0, stream>>>(ybf, nullptr, Woth, nullptr, (float*)d_out, BT_, 512, 512);
}